// Round 8
// baseline (205.712 us; speedup 1.0000x reference)
//
#include <hip/hip_runtime.h>
#include <hip/hip_bf16.h>

// ---- problem constants ----
#define BB 2
#define SS 2048
#define DMODEL 1024
#define NHEADS 16
#define DHEAD 64
#define MTOT (BB*SS)      // 4096
#define NQKV 3072
#define QSCALE 0.18033688011112042f   // 0.125 * log2(e), folded into Q at projection

typedef short bh8 __attribute__((ext_vector_type(8)));   // 8 bf16 (4 VGPRs)
typedef float fx4 __attribute__((ext_vector_type(4)));   // MFMA accumulator
typedef unsigned int ux2 __attribute__((ext_vector_type(2)));

__device__ __forceinline__ short f2bs(float f) {
    __hip_bfloat16 h = __float2bfloat16(f);
    return *reinterpret_cast<short*>(&h);
}

__device__ __forceinline__ unsigned pk_bf16(float a, float b) {
    __hip_bfloat162 h = __float22bfloat162_rn(make_float2(a, b));
    return *reinterpret_cast<unsigned*>(&h);
}

// verified lane transform: inputs ea,eb = two row-tile fragments (reg axis =
// 4 consecutive rows at quad*4); output = uint4 whose 8 bf16 are 8 consecutive
// rows at quad*8 within the 32-row span, same column (ln). Axis-agnostic.
__device__ __forceinline__ uint4 pack32(fx4 ea, fx4 eb) {
    unsigned xa = pk_bf16(ea[0], ea[1]);
    unsigned ya = pk_bf16(ea[2], ea[3]);
    unsigned xb = pk_bf16(eb[0], eb[1]);
    unsigned yb = pk_bf16(eb[2], eb[3]);
    ux2 u   = __builtin_amdgcn_permlane32_swap(xa, xb, false, false);
    ux2 d02 = __builtin_amdgcn_permlane16_swap(u.x, u.y, false, false);
    ux2 u2  = __builtin_amdgcn_permlane32_swap(ya, yb, false, false);
    ux2 d13 = __builtin_amdgcn_permlane16_swap(u2.x, u2.y, false, false);
    uint4 r;
    r.x = d02.x; r.y = d13.x; r.z = d02.y; r.w = d13.y;
    return r;
}

// async global->LDS, 16B per lane. LDS dest wave-uniform base + lane*16.
__device__ __forceinline__ void gload_lds16(const short* g, short* l) {
    __builtin_amdgcn_global_load_lds(
        (const __attribute__((address_space(1))) unsigned int*)g,
        (__attribute__((address_space(3))) unsigned int*)l, 16, 0, 0);
}

// ---------------- prep: cvt emb (blocks 0..4095) + transpose weights (4096..5119) ----------------
__global__ __launch_bounds__(256) void prep(
        const float* __restrict__ emb, short* __restrict__ Xbf,
        const float* __restrict__ Wq, const float* __restrict__ Wk,
        const float* __restrict__ Wv, const float* __restrict__ Wo,
        short* __restrict__ Wt_qkv, short* __restrict__ Wot) {
    __shared__ float tile[64][65];
    int bid = blockIdx.x, tid = threadIdx.x;
    if (bid < 4096) {
        int i = (bid * 256 + tid) * 4;          // exactly covers MTOT*DMODEL
        float4 v = *(const float4*)(emb + i);
        short4 o;
        o.x = f2bs(v.x); o.y = f2bs(v.y); o.z = f2bs(v.z); o.w = f2bs(v.w);
        *(short4*)(Xbf + i) = o;
    } else {
        int b2 = bid - 4096;
        int bx = b2 & 15, by = (b2 >> 4) & 15, z = b2 >> 8;
        const float* src = (z == 0) ? Wq : (z == 1) ? Wk : (z == 2) ? Wv : Wo;
        short* dst = (z == 3) ? Wot : (Wt_qkv + (size_t)z * 1024 * 1024);
        int n0 = bx * 64, k0 = by * 64;
        int tx = tid & 63, ty = tid >> 6;
        for (int j = 0; j < 16; j++) {
            int r = ty + j * 4;
            tile[r][tx] = src[(size_t)(k0 + r) * 1024 + n0 + tx];
        }
        __syncthreads();
        // vectorized write-out: short4 per store (was 16x scalar 2B stores).
        // LDS read banks: (4*c4 + i*65 + r) & 31 -> 2-way aliasing only (free).
        int c4 = tid & 15, rr = tid >> 4;
        #pragma unroll
        for (int pass = 0; pass < 4; pass++) {
            int r = rr + pass * 16;
            short4 o;
            o.x = f2bs(tile[c4 * 4 + 0][r]);
            o.y = f2bs(tile[c4 * 4 + 1][r]);
            o.z = f2bs(tile[c4 * 4 + 2][r]);
            o.w = f2bs(tile[c4 * 4 + 3][r]);
            *(short4*)&dst[(size_t)(n0 + r) * 1024 + k0 + c4 * 4] = o;
        }
    }
}

// ---------------- bt-GEMM (templated): C[m][n] = sum_k A[m][k]*Bt[n][k] ----------------
// BMxBN block, 4 waves (2x2), 3-stage global_load_lds pipeline with raw
// s_waitcnt vmcnt(CPW)+s_barrier (never vmcnt(0) mid-loop). XCD-aware 1D grid.
// v8: ALL epilogues barrier-free and vectorized.
//  - MODE0 Q/K: swapped acc (row=d) + permlane pack32 over nt-pairs -> lane
//    holds 8 consecutive d at fixed s -> 8x 16B stores. No LDS, no barriers.
//  - MODE0 V: non-swapped acc (row=m) + pack32 over mt-pairs -> 8 consecutive
//    s at fixed d -> 16B V^T stores (verified since round 6).
//  - MODE1: swapped acc (row=n) -> lane's 4 regs = 4 consecutive n -> fx4
//    16B fp32 stores (was 32 scalar dwords), bias via fx4 loads.
template<int BM, int BN, int NN, int MODE>
__global__ __launch_bounds__(256) void gemm_bt_t(
        const short* __restrict__ A, const short* __restrict__ Bt,
        const float* __restrict__ bq, const float* __restrict__ bk,
        const float* __restrict__ bv, const float* __restrict__ bo,
        short* __restrict__ Qout, short* __restrict__ Kout,
        short* __restrict__ Vtout, float* __restrict__ Cout) {
    const int K = 1024;
    constexpr int ROWS = BM + BN;        // combined A+B panel rows per k-tile
    constexpr int CPW  = ROWS / 64;      // 16-row staging chunks per wave
    constexpr int MBK  = MTOT / BM;      // m-blocks
    constexpr int STRIP = MBK / 8;       // m-tiles per XCD strip
    constexpr int MT = BM / 32, NT = BN / 32;
    __shared__ __align__(16) short S[3][ROWS * 32];

    int tid = threadIdx.x;
    int w = tid >> 6, l = tid & 63, quad = l >> 4, ln = l & 15;
    int wm = w & 1, wn = w >> 1;

    // XCD-aware decode: id%8 ~ XCD; XCD owns M-strip [xcd*STRIP, xcd*STRIP+STRIP)
    int id = blockIdx.x;
    int xcd = id & 7, local = id >> 3;
    int mi = xcd * STRIP + (local % STRIP);
    int ni = local / STRIP;
    int m0 = mi * BM, n0 = ni * BN;

    // block-uniform output kind (MODE 0): 0=Q 1=K 2=V
    const int which = (MODE == 0) ? (n0 >> 10) : 2;
    // swapped MFMA operands everywhere except the MODE0 V path
    const bool swp = (MODE == 1) || (which != 2);

    // staging chunk map: chunk c = w*CPW+j covers panel rows [c*16, c*16+16);
    // panel rows [0,BM) = A tile rows, [BM,ROWS) = B tile rows.
    const short* gsrc[CPW];
    int loff[CPW];
    #pragma unroll
    for (int j = 0; j < CPW; j++) {
        int r0 = (w * CPW + j) * 16;
        int row = r0 + (l >> 2);
        gsrc[j] = (r0 < BM ? A + (size_t)(m0 + row) * K
                           : Bt + (size_t)(n0 + row - BM) * K) + (l & 3) * 8;
        loff[j] = r0 * 32;
    }

    short *sC = &S[0][0], *sN = &S[1][0], *sN2 = &S[2][0];
    #pragma unroll
    for (int j = 0; j < CPW; j++) gload_lds16(gsrc[j], sC + loff[j]);
    #pragma unroll
    for (int j = 0; j < CPW; j++) gload_lds16(gsrc[j] + 32, sN + loff[j]);

    fx4 acc[MT][NT] = {};
    for (int it = 0; it < 32; ++it) {
        if (it < 31) {
            if constexpr (CPW == 4)
                asm volatile("s_waitcnt vmcnt(4)\n\ts_barrier" ::: "memory");
            else
                asm volatile("s_waitcnt vmcnt(3)\n\ts_barrier" ::: "memory");
        } else {
            asm volatile("s_waitcnt vmcnt(0)\n\ts_barrier" ::: "memory");
        }
        if (it < 30) {
            int k0 = (it + 2) * 32;
            #pragma unroll
            for (int j = 0; j < CPW; j++) gload_lds16(gsrc[j] + k0, sN2 + loff[j]);
        }
        bh8 af[MT], bf[NT];
        #pragma unroll
        for (int mt = 0; mt < MT; mt++)
            af[mt] = *(const bh8*)&sC[(wm * (BM / 2) + mt * 16 + ln) * 32 + quad * 8];
        #pragma unroll
        for (int nt = 0; nt < NT; nt++)
            bf[nt] = *(const bh8*)&sC[(BM + wn * (BN / 2) + nt * 16 + ln) * 32 + quad * 8];
        if (!swp) {
            #pragma unroll
            for (int mt = 0; mt < MT; mt++)
                #pragma unroll
                for (int nt = 0; nt < NT; nt++)
                    acc[mt][nt] = __builtin_amdgcn_mfma_f32_16x16x32_bf16(af[mt], bf[nt], acc[mt][nt], 0, 0, 0);
        } else {
            // swapped: C row axis = n, col axis = m
            #pragma unroll
            for (int mt = 0; mt < MT; mt++)
                #pragma unroll
                for (int nt = 0; nt < NT; nt++)
                    acc[mt][nt] = __builtin_amdgcn_mfma_f32_16x16x32_bf16(bf[nt], af[mt], acc[mt][nt], 0, 0, 0);
        }
        short* t;
        t = sC; sC = sN; sN = sN2; sN2 = t;
    }

    if constexpr (MODE == 0) {
        int nbase = n0 + wn * 64;
        int nn0 = nbase & 1023;          // multiple of 64 (this wave's 64-d base)
        int h = nn0 >> 6;
        int mbase_w = m0 + wm * 64;      // 64-aligned, never crosses batch
        int bb_ = mbase_w >> 11, s0 = mbase_w & 2047;

        if (which == 2) {
            // V (non-swapped acc: row=m, col=d=nt*16+ln). Bias per-lane, then
            // pack32 over mt-pairs -> 8 consecutive s at fixed d; 16B stores.
            #pragma unroll
            for (int nt = 0; nt < NT; nt++) {
                float bias = bv[nn0 + nt * 16 + ln];
                #pragma unroll
                for (int mt = 0; mt < MT; mt++)
                    #pragma unroll
                    for (int r = 0; r < 4; r++)
                        acc[mt][nt][r] += bias;
            }
            #pragma unroll
            for (int nt = 0; nt < NT; nt++) {
                int d = nt * 16 + ln;
                short* vrow = Vtout + ((size_t)(bb_ * 16 + h) * 64 + d) * 2048 + s0;
                #pragma unroll
                for (int mp = 0; mp < MT / 2; mp++) {
                    uint4 pk = pack32(acc[2 * mp][nt], acc[2 * mp + 1][nt]);
                    *(uint4*)(vrow + (mp * 32 + quad * 8)) = pk;
                }
            }
        } else {
            // Q/K (swapped acc: d = nt*16+quad*4+r, s = mt*16+ln). Bias+scale
            // in fragment space (fx4 bias loads), then pack32 over nt-pairs ->
            // lane holds 8 consecutive d at fixed s; 16B [s][d] stores.
            const float* bptr = (which == 0) ? bq : bk;
            float scl = (which == 0) ? QSCALE : 1.0f;
            short* out = (which == 0) ? Qout : Kout;
            fx4 bv4[NT];
            #pragma unroll
            for (int nt = 0; nt < NT; nt++)
                bv4[nt] = *(const fx4*)&bptr[nn0 + nt * 16 + quad * 4];
            #pragma unroll
            for (int mt = 0; mt < MT; mt++)
                #pragma unroll
                for (int nt = 0; nt < NT; nt++)
                    #pragma unroll
                    for (int r = 0; r < 4; r++)
                        acc[mt][nt][r] = (acc[mt][nt][r] + bv4[nt][r]) * scl;
            #pragma unroll
            for (int mt = 0; mt < MT; mt++) {
                int s_ = s0 + mt * 16 + ln;
                short* crow = out + (((size_t)(bb_ * 16 + h) * 2048) + s_) * 64;
                #pragma unroll
                for (int np = 0; np < NT / 2; np++) {
                    uint4 pk = pack32(acc[mt][2 * np], acc[mt][2 * np + 1]);
                    *(uint4*)(crow + (np * 32 + quad * 8)) = pk;
                }
            }
        }
    } else {
        // MODE1 (swapped acc: n = nt*16+quad*4+r, m = mt*16+ln): fx4 stores.
        int nbase = n0 + wn * (BN / 2);
        fx4 bv4[NT];
        #pragma unroll
        for (int nt = 0; nt < NT; nt++)
            bv4[nt] = *(const fx4*)&bo[nbase + nt * 16 + quad * 4];
        #pragma unroll
        for (int mt = 0; mt < MT; mt++) {
            int m = m0 + wm * (BM / 2) + mt * 16 + ln;
            #pragma unroll
            for (int nt = 0; nt < NT; nt++) {
                fx4 v = acc[mt][nt] + bv4[nt];
                *(fx4*)&Cout[(size_t)m * 1024 + nbase + nt * 16 + quad * 4] = v;
            }
        }
    }
}

// ---------------- flash attention: 2x2 wave split (q x key), fused epilogue ----------------
// v5 (unchanged): wave (wq,wk) owns 32 q-rows x 32 keys; per-wave LDS reads
// data-minimal; key-partial O reduced across the wk pair in the epilogue;
// l = mfma(ones, P) on the matrix pipe; s_setprio(1) around MFMA clusters.
__global__ __launch_bounds__(256, 4) void flash_attn(
        const short* __restrict__ Q, const short* __restrict__ Kg,
        const short* __restrict__ Vt, short* __restrict__ Ctx) {
    // 32 KB: [K buf0 | K buf1 | V buf0 | V buf1], 4096 shorts each.
    // Epilogue reuse: floats [0,2176) per-wq transpose scratch,
    // [2176,6272) o-reduce (2 x 2048), [6272,6336) l-reduce.
    __shared__ __align__(16) short SH[16384];

    int tid = threadIdx.x;
    int w = tid >> 6, l = tid & 63, quad = l >> 4, ln = l & 15;
    int wq = w & 1, wk = w >> 1;
    // XCD-aware decode: 4 bh per XCD, 32 q-blocks per bh
    int id = blockIdx.x;
    int xcd = id & 7, local = id >> 3;           // local 0..127
    int bh = xcd * 4 + (local & 3);
    int qx = local >> 2;                         // 0..31
    int qblk = qx * 64 + wq * 32;                // this wave's 32 q-rows
    int b = bh >> 4, h = bh & 15;
    const short* Qb = Q  + (size_t)bh * 2048 * 64;
    const short* Kb = Kg + (size_t)bh * 2048 * 64;
    const short* Vb = Vt + (size_t)bh * 64 * 2048;
    int swz = ln & 7;

    // Q fragments (B-operand), 32 rows
    bh8 qf[2][2];
    #pragma unroll
    for (int qt = 0; qt < 2; qt++)
        #pragma unroll
        for (int c = 0; c < 2; c++)
            qf[qt][c] = *(const bh8*)&Qb[(size_t)(qblk + qt * 16 + ln) * 64 + c * 32 + quad * 8];

    // all-ones bf16 A-fragment for the l row-sum MFMA
    union { short s[8]; bh8 v; } one_;
    #pragma unroll
    for (int j = 0; j < 8; j++) one_.s[j] = 0x3F80;
    bh8 onesv = one_.v;

    // DMA staging map (block-cooperative, by raw wave id w): chunk c = w*2+j
    // covers tile rows [c*8, c*8+8). Linear LDS dest: lane l -> c*512 + l*8.
    // Global source pre-swizzled so LDS[row][p] holds col-group p^(row&7).
    const short* srcK[2]; const short* srcV[2]; int dstoff[2];
    #pragma unroll
    for (int j = 0; j < 2; j++) {
        int c = w * 2 + j;
        int row = c * 8 + (l >> 3);
        int pg = (l & 7) ^ (row & 7);
        srcK[j] = Kb + row * 64 + pg * 8;
        srcV[j] = Vb + (size_t)row * 2048 + pg * 8;
        dstoff[j] = c * 512;
    }

    // prologue: stage tile 0 into buf 0
    #pragma unroll
    for (int j = 0; j < 2; j++) {
        gload_lds16(srcK[j], SH + dstoff[j]);
        gload_lds16(srcV[j], SH + 8192 + dstoff[j]);
    }

    fx4 o[2][4] = {};
    fx4 lacc[2] = {};

    for (int it = 0; it < 32; ++it) {
        int koff = (it & 1) ? 4096 : 0;
        // tile `it` DMA complete + all waves done reading buf it^1.
        asm volatile("s_waitcnt vmcnt(0) lgkmcnt(0)\n\ts_barrier" ::: "memory");
        if (it < 31) {   // issue next-tile DMA into the other buffer; waited next iter
            int noff = koff ^ 4096;
            int kg = (it + 1) * 4096, vg = (it + 1) * 64;
            #pragma unroll
            for (int j = 0; j < 2; j++) {
                gload_lds16(srcK[j] + kg, SH + noff + dstoff[j]);
                gload_lds16(srcV[j] + vg, SH + 8192 + noff + dstoff[j]);
            }
        }
        const short* ksb = SH + koff;
        const short* vsb = SH + 8192 + koff;

        // S^T[key][q] = K * Q^T  (this wave: keys wk*32.., 32 q-cols)
        bh8 kf[2][2];
        #pragma unroll
        for (int mt = 0; mt < 2; mt++) {
            int krow = (wk * 32 + mt * 16 + ln) * 64;
            kf[mt][0] = *(const bh8*)&ksb[krow + ((quad ^ swz) * 8)];
            kf[mt][1] = *(const bh8*)&ksb[krow + (((quad + 4) ^ swz) * 8)];
        }
        fx4 s[2][2] = {};
        __builtin_amdgcn_s_setprio(1);
        #pragma unroll
        for (int mt = 0; mt < 2; mt++)
            #pragma unroll
            for (int qt = 0; qt < 2; qt++) {
                s[qt][mt] = __builtin_amdgcn_mfma_f32_16x16x32_bf16(kf[mt][0], qf[qt][0], s[qt][mt], 0, 0, 0);
                s[qt][mt] = __builtin_amdgcn_mfma_f32_16x16x32_bf16(kf[mt][1], qf[qt][1], s[qt][mt], 0, 0, 0);
            }
        __builtin_amdgcn_s_setprio(0);

        // P = exp2(S), packed to PV B-fragments entirely in-register
        bh8 pf[2];
        #pragma unroll
        for (int qt = 0; qt < 2; qt++) {
            fx4 e0, e1;
            #pragma unroll
            for (int r = 0; r < 4; r++) {
                e0[r] = __builtin_amdgcn_exp2f(s[qt][0][r]);
                e1[r] = __builtin_amdgcn_exp2f(s[qt][1][r]);
            }
            uint4 pk = pack32(e0, e1);
            union { uint4 u; bh8 v; } pc;
            pc.u = pk;
            pf[qt] = pc.v;
        }

        // O^T += V^T * P^T over this wave's 32 keys; l via ones-MFMA row-sum
        __builtin_amdgcn_s_setprio(1);
        #pragma unroll
        for (int dt = 0; dt < 4; dt++) {
            bh8 vf = *(const bh8*)&vsb[(dt * 16 + ln) * 64 + (((wk * 4 + quad) ^ swz) * 8)];
            o[0][dt] = __builtin_amdgcn_mfma_f32_16x16x32_bf16(vf, pf[0], o[0][dt], 0, 0, 0);
            o[1][dt] = __builtin_amdgcn_mfma_f32_16x16x32_bf16(vf, pf[1], o[1][dt], 0, 0, 0);
        }
        lacc[0] = __builtin_amdgcn_mfma_f32_16x16x32_bf16(onesv, pf[0], lacc[0], 0, 0, 0);
        lacc[1] = __builtin_amdgcn_mfma_f32_16x16x32_bf16(onesv, pf[1], lacc[1], 0, 0, 0);
        __builtin_amdgcn_s_setprio(0);
    }

    // all waves done reading K/V LDS before reusing it as epilogue scratch
    asm volatile("s_waitcnt vmcnt(0) lgkmcnt(0)\n\ts_barrier" ::: "memory");

    float* R  = (float*)SH + 2176;            // o-reduce: 2 regions x 2048 floats
    float* R2 = (float*)SH + 2176 + 4096;     // l-reduce: 2 x 32 floats

    // wk=1 waves publish their key-partial O and l
    if (wk == 1) {
        float* Rw = R + wq * 2048;
        #pragma unroll
        for (int qt = 0; qt < 2; qt++)
            #pragma unroll
            for (int dt = 0; dt < 4; dt++)
                *(fx4*)&Rw[(((qt * 4 + dt) * 4 + quad) * 16 + ln) * 4] = o[qt][dt];
        if (quad == 0) {
            R2[wq * 32 + 0 * 16 + ln] = lacc[0][0];
            R2[wq * 32 + 1 * 16 + ln] = lacc[1][0];
        }
    }
    asm volatile("s_waitcnt lgkmcnt(0)\n\ts_barrier" ::: "memory");

    if (wk == 0) {
        // reduce across the wk pair
        float* Rw = R + wq * 2048;
        float linv[2];
        #pragma unroll
        for (int qt = 0; qt < 2; qt++) {
            #pragma unroll
            for (int dt = 0; dt < 4; dt++)
                o[qt][dt] += *(const fx4*)&Rw[(((qt * 4 + dt) * 4 + quad) * 16 + ln) * 4];
            float lf = lacc[qt][0] + R2[wq * 32 + qt * 16 + ln];
            linv[qt] = 1.0f / lf;
        }
        // O^T -> rows via per-wave LDS transpose, scale by 1/l, bf16 out.
        float* PsF = (float*)SH + wq * 1088;   // 16 rows x 68-float stride
        int row = l >> 2, seg = l & 3;
        #pragma unroll
        for (int qt = 0; qt < 2; qt++) {
            #pragma unroll
            for (int dt = 0; dt < 4; dt++)
                *(fx4*)&PsF[ln * 68 + dt * 16 + quad * 4] = o[qt][dt];
            asm volatile("s_waitcnt lgkmcnt(0)" ::: "memory");
            float invr = __shfl(linv[qt], row);    // lane `row` holds l for q-row `row`
            int q = qblk + qt * 16 + row;
            short* crow = Ctx + ((size_t)(b * 2048 + q)) * 1024 + h * 64 + seg * 16;
            union { short s[8]; uint4 u; } o0, o1;
            #pragma unroll
            for (int j = 0; j < 2; j++) {
                fx4 v = *(const fx4*)&PsF[row * 68 + seg * 16 + j * 4];
                o0.s[j * 4 + 0] = f2bs(v[0] * invr);
                o0.s[j * 4 + 1] = f2bs(v[1] * invr);
                o0.s[j * 4 + 2] = f2bs(v[2] * invr);
                o0.s[j * 4 + 3] = f2bs(v[3] * invr);
            }
            #pragma unroll
            for (int j = 2; j < 4; j++) {
                fx4 v = *(const fx4*)&PsF[row * 68 + seg * 16 + j * 4];
                o1.s[(j - 2) * 4 + 0] = f2bs(v[0] * invr);
                o1.s[(j - 2) * 4 + 1] = f2bs(v[1] * invr);
                o1.s[(j - 2) * 4 + 2] = f2bs(v[2] * invr);
                o1.s[(j - 2) * 4 + 3] = f2bs(v[3] * invr);
            }
            *(uint4*)&crow[0] = o0.u;
            *(uint4*)&crow[8] = o1.u;
            asm volatile("s_waitcnt lgkmcnt(0)" ::: "memory");  // reads done before next qt overwrites
        }
    }
}

extern "C" void kernel_launch(void* const* d_in, const int* in_sizes, int n_in,
                              void* d_out, int out_size, void* d_ws, size_t ws_size,
                              hipStream_t stream) {
    const float* emb = (const float*)d_in[0];
    const float* Wq  = (const float*)d_in[1];
    const float* bq  = (const float*)d_in[2];
    const float* Wk  = (const float*)d_in[3];
    const float* bk  = (const float*)d_in[4];
    const float* Wv  = (const float*)d_in[5];
    const float* bv  = (const float*)d_in[6];
    const float* Wo  = (const float*)d_in[7];
    const float* bo  = (const float*)d_in[8];

    char* ws = (char*)d_ws;
    const size_t MB = 1024 * 1024;
    short* Xbf  = (short*)(ws + 0);          // A panel for QKV gemm
    short* Ctx  = (short*)(ws + 0);          // flash bf16 output (overlays Xbf,
                                             // which is dead after the QKV gemm)
    short* Wt   = (short*)(ws + 8 * MB);
    short* Wot  = (short*)(ws + 17 * MB);
    short* Qb   = (short*)(ws + 19 * MB);    // pre-scaled by QSCALE
    short* Kb   = (short*)(ws + 27 * MB);
    short* Vtb  = (short*)(ws + 35 * MB);    // [B,H,Dh,S]

    // fused prep: emb->bf16 (4096 blocks) + 4x weight transpose (1024 blocks)
    prep<<<5120, 256, 0, stream>>>(emb, Xbf, Wq, Wk, Wv, Wo, Wt, Wot);
    // QKV projection: 128x128 tiles, 32x24 = 768 blocks, XCD-swizzled
    gemm_bt_t<128, 128, NQKV, 0><<<768, 256, 0, stream>>>(
        Xbf, Wt, bq, bk, bv, nullptr, Qb, Kb, Vtb, nullptr);
    // attention: 1024 blocks = 4/CU, 64 q-rows each, 2x2 wave split, fused bf16 out
    flash_attn<<<1024, 256, 0, stream>>>(Qb, Kb, Vtb, Ctx);
    // output projection: 64x128 tiles, 64x8 = 512 blocks, XCD-swizzled
    gemm_bt_t<64, 128, DMODEL, 1><<<512, 256, 0, stream>>>(
        Ctx, Wot, nullptr, nullptr, nullptr, bo, nullptr, nullptr, nullptr, (float*)d_out);
}

// Round 9
// 200.180 us; speedup vs baseline: 1.0276x; 1.0276x over previous
//
#include <hip/hip_runtime.h>
#include <hip/hip_bf16.h>

// ---- problem constants ----
#define BB 2
#define SS 2048
#define DMODEL 1024
#define NHEADS 16
#define DHEAD 64
#define MTOT (BB*SS)      // 4096
#define NQKV 3072
#define QSCALE 0.18033688011112042f   // 0.125 * log2(e), folded into Q at projection

typedef short bh8 __attribute__((ext_vector_type(8)));   // 8 bf16 (4 VGPRs)
typedef float fx4 __attribute__((ext_vector_type(4)));   // MFMA accumulator
typedef unsigned int ux2 __attribute__((ext_vector_type(2)));

__device__ __forceinline__ short f2bs(float f) {
    __hip_bfloat16 h = __float2bfloat16(f);
    return *reinterpret_cast<short*>(&h);
}

__device__ __forceinline__ unsigned pk_bf16(float a, float b) {
    __hip_bfloat162 h = __float22bfloat162_rn(make_float2(a, b));
    return *reinterpret_cast<unsigned*>(&h);
}

// verified lane transform: inputs ea,eb = two row-tile fragments (reg axis =
// 4 consecutive rows at quad*4); output = uint4 whose 8 bf16 are 8 consecutive
// rows at quad*8 within the 32-row span, same column (ln). Axis-agnostic.
__device__ __forceinline__ uint4 pack32(fx4 ea, fx4 eb) {
    unsigned xa = pk_bf16(ea[0], ea[1]);
    unsigned ya = pk_bf16(ea[2], ea[3]);
    unsigned xb = pk_bf16(eb[0], eb[1]);
    unsigned yb = pk_bf16(eb[2], eb[3]);
    ux2 u   = __builtin_amdgcn_permlane32_swap(xa, xb, false, false);
    ux2 d02 = __builtin_amdgcn_permlane16_swap(u.x, u.y, false, false);
    ux2 u2  = __builtin_amdgcn_permlane32_swap(ya, yb, false, false);
    ux2 d13 = __builtin_amdgcn_permlane16_swap(u2.x, u2.y, false, false);
    uint4 r;
    r.x = d02.x; r.y = d13.x; r.z = d02.y; r.w = d13.y;
    return r;
}

// async global->LDS, 16B per lane. LDS dest wave-uniform base + lane*16.
__device__ __forceinline__ void gload_lds16(const short* g, short* l) {
    __builtin_amdgcn_global_load_lds(
        (const __attribute__((address_space(1))) unsigned int*)g,
        (__attribute__((address_space(3))) unsigned int*)l, 16, 0, 0);
}

// ---------------- prep: cvt emb (blocks 0..4095) + transpose weights (4096..5119) ----------------
__global__ __launch_bounds__(256) void prep(
        const float* __restrict__ emb, short* __restrict__ Xbf,
        const float* __restrict__ Wq, const float* __restrict__ Wk,
        const float* __restrict__ Wv, const float* __restrict__ Wo,
        short* __restrict__ Wt_qkv, short* __restrict__ Wot) {
    __shared__ float tile[64][65];
    int bid = blockIdx.x, tid = threadIdx.x;
    if (bid < 4096) {
        int i = (bid * 256 + tid) * 4;          // exactly covers MTOT*DMODEL
        float4 v = *(const float4*)(emb + i);
        short4 o;
        o.x = f2bs(v.x); o.y = f2bs(v.y); o.z = f2bs(v.z); o.w = f2bs(v.w);
        *(short4*)(Xbf + i) = o;
    } else {
        int b2 = bid - 4096;
        int bx = b2 & 15, by = (b2 >> 4) & 15, z = b2 >> 8;
        const float* src = (z == 0) ? Wq : (z == 1) ? Wk : (z == 2) ? Wv : Wo;
        short* dst = (z == 3) ? Wot : (Wt_qkv + (size_t)z * 1024 * 1024);
        int n0 = bx * 64, k0 = by * 64;
        int tx = tid & 63, ty = tid >> 6;
        for (int j = 0; j < 16; j++) {
            int r = ty + j * 4;
            tile[r][tx] = src[(size_t)(k0 + r) * 1024 + n0 + tx];
        }
        __syncthreads();
        // vectorized write-out: short4 per store (was 16x scalar 2B stores).
        // LDS read banks: 2-way aliasing only (free, m136).
        int c4 = tid & 15, rr = tid >> 4;
        #pragma unroll
        for (int pass = 0; pass < 4; pass++) {
            int r = rr + pass * 16;
            short4 o;
            o.x = f2bs(tile[c4 * 4 + 0][r]);
            o.y = f2bs(tile[c4 * 4 + 1][r]);
            o.z = f2bs(tile[c4 * 4 + 2][r]);
            o.w = f2bs(tile[c4 * 4 + 3][r]);
            *(short4*)&dst[(size_t)(n0 + r) * 1024 + k0 + c4 * 4] = o;
        }
    }
}

// ---------------- bt-GEMM (templated): C[m][n] = sum_k A[m][k]*Bt[n][k] ----------------
// BMxBN block, 4 waves (2x2), 3-stage global_load_lds pipeline with raw
// s_waitcnt vmcnt(CPW)+s_barrier (never vmcnt(0) mid-loop). XCD-aware 1D grid.
// v9: __launch_bounds__(256,4) caps VGPR at 128 — v8's epilogue pushed the
// allocator to 136, over the 128 occupancy cliff (4->2 waves/SIMD, m69),
// costing 8 µs on the QKV gemm. Epilogues rewritten register-lean: bias folded
// directly into the pack/store loop (no bias arrays, no acc-rewrite pre-pass).
//  - MODE0 Q/K: swapped acc (row=d) + pack32 over nt-pairs -> 8x 16B stores.
//  - MODE0 V: non-swapped acc (row=m) + pack32 over mt-pairs -> 16B V^T stores.
//  - MODE1: swapped acc (row=n) -> fx4 16B fp32 stores.
template<int BM, int BN, int NN, int MODE>
__global__ __launch_bounds__(256, 4) void gemm_bt_t(
        const short* __restrict__ A, const short* __restrict__ Bt,
        const float* __restrict__ bq, const float* __restrict__ bk,
        const float* __restrict__ bv, const float* __restrict__ bo,
        short* __restrict__ Qout, short* __restrict__ Kout,
        short* __restrict__ Vtout, float* __restrict__ Cout) {
    const int K = 1024;
    constexpr int ROWS = BM + BN;        // combined A+B panel rows per k-tile
    constexpr int CPW  = ROWS / 64;      // 16-row staging chunks per wave
    constexpr int MBK  = MTOT / BM;      // m-blocks
    constexpr int STRIP = MBK / 8;       // m-tiles per XCD strip
    constexpr int MT = BM / 32, NT = BN / 32;
    __shared__ __align__(16) short S[3][ROWS * 32];

    int tid = threadIdx.x;
    int w = tid >> 6, l = tid & 63, quad = l >> 4, ln = l & 15;
    int wm = w & 1, wn = w >> 1;

    // XCD-aware decode: id%8 ~ XCD; XCD owns M-strip [xcd*STRIP, xcd*STRIP+STRIP)
    int id = blockIdx.x;
    int xcd = id & 7, local = id >> 3;
    int mi = xcd * STRIP + (local % STRIP);
    int ni = local / STRIP;
    int m0 = mi * BM, n0 = ni * BN;

    // block-uniform output kind (MODE 0): 0=Q 1=K 2=V
    const int which = (MODE == 0) ? (n0 >> 10) : 2;
    // swapped MFMA operands everywhere except the MODE0 V path
    const bool swp = (MODE == 1) || (which != 2);

    // staging chunk map: chunk c = w*CPW+j covers panel rows [c*16, c*16+16);
    // panel rows [0,BM) = A tile rows, [BM,ROWS) = B tile rows.
    const short* gsrc[CPW];
    int loff[CPW];
    #pragma unroll
    for (int j = 0; j < CPW; j++) {
        int r0 = (w * CPW + j) * 16;
        int row = r0 + (l >> 2);
        gsrc[j] = (r0 < BM ? A + (size_t)(m0 + row) * K
                           : Bt + (size_t)(n0 + row - BM) * K) + (l & 3) * 8;
        loff[j] = r0 * 32;
    }

    short *sC = &S[0][0], *sN = &S[1][0], *sN2 = &S[2][0];
    #pragma unroll
    for (int j = 0; j < CPW; j++) gload_lds16(gsrc[j], sC + loff[j]);
    #pragma unroll
    for (int j = 0; j < CPW; j++) gload_lds16(gsrc[j] + 32, sN + loff[j]);

    fx4 acc[MT][NT] = {};
    for (int it = 0; it < 32; ++it) {
        if (it < 31) {
            if constexpr (CPW == 4)
                asm volatile("s_waitcnt vmcnt(4)\n\ts_barrier" ::: "memory");
            else
                asm volatile("s_waitcnt vmcnt(3)\n\ts_barrier" ::: "memory");
        } else {
            asm volatile("s_waitcnt vmcnt(0)\n\ts_barrier" ::: "memory");
        }
        if (it < 30) {
            int k0 = (it + 2) * 32;
            #pragma unroll
            for (int j = 0; j < CPW; j++) gload_lds16(gsrc[j] + k0, sN2 + loff[j]);
        }
        bh8 af[MT], bf[NT];
        #pragma unroll
        for (int mt = 0; mt < MT; mt++)
            af[mt] = *(const bh8*)&sC[(wm * (BM / 2) + mt * 16 + ln) * 32 + quad * 8];
        #pragma unroll
        for (int nt = 0; nt < NT; nt++)
            bf[nt] = *(const bh8*)&sC[(BM + wn * (BN / 2) + nt * 16 + ln) * 32 + quad * 8];
        if (!swp) {
            #pragma unroll
            for (int mt = 0; mt < MT; mt++)
                #pragma unroll
                for (int nt = 0; nt < NT; nt++)
                    acc[mt][nt] = __builtin_amdgcn_mfma_f32_16x16x32_bf16(af[mt], bf[nt], acc[mt][nt], 0, 0, 0);
        } else {
            // swapped: C row axis = n, col axis = m
            #pragma unroll
            for (int mt = 0; mt < MT; mt++)
                #pragma unroll
                for (int nt = 0; nt < NT; nt++)
                    acc[mt][nt] = __builtin_amdgcn_mfma_f32_16x16x32_bf16(bf[nt], af[mt], acc[mt][nt], 0, 0, 0);
        }
        short* t;
        t = sC; sC = sN; sN = sN2; sN2 = t;
    }

    if constexpr (MODE == 0) {
        int nbase = n0 + wn * 64;
        int nn0 = nbase & 1023;          // multiple of 64 (this wave's 64-d base)
        int h = nn0 >> 6;
        int mbase_w = m0 + wm * 64;      // 64-aligned, never crosses batch
        int bb_ = mbase_w >> 11, s0 = mbase_w & 2047;

        if (which == 2) {
            // V (non-swapped acc: row=m, col=d=nt*16+ln). Bias folded into the
            // pack loop (lane-scalar per nt); pack32 over mt-pairs -> 8
            // consecutive s at fixed d; 16B stores.
            #pragma unroll
            for (int nt = 0; nt < NT; nt++) {
                float bias = bv[nn0 + nt * 16 + ln];
                fx4 bb4 = {bias, bias, bias, bias};
                int d = nt * 16 + ln;
                short* vrow = Vtout + ((size_t)(bb_ * 16 + h) * 64 + d) * 2048 + s0;
                #pragma unroll
                for (int mp = 0; mp < MT / 2; mp++) {
                    uint4 pk = pack32(acc[2 * mp][nt] + bb4, acc[2 * mp + 1][nt] + bb4);
                    *(uint4*)(vrow + (mp * 32 + quad * 8)) = pk;
                }
            }
        } else {
            // Q/K (swapped acc: d = nt*16+quad*4+r, s = mt*16+ln). Bias+scale
            // folded into the pack loop (fx4 loads, CSE'd across mt); pack32
            // over nt-pairs -> 8 consecutive d at fixed s; 16B [s][d] stores.
            const float* bptr = (which == 0) ? bq : bk;
            float scl = (which == 0) ? QSCALE : 1.0f;
            short* out = (which == 0) ? Qout : Kout;
            #pragma unroll
            for (int mt = 0; mt < MT; mt++) {
                int s_ = s0 + mt * 16 + ln;
                short* crow = out + (((size_t)(bb_ * 16 + h) * 2048) + s_) * 64;
                #pragma unroll
                for (int np = 0; np < NT / 2; np++) {
                    fx4 ba = *(const fx4*)&bptr[nn0 + (2 * np) * 16 + quad * 4];
                    fx4 bb = *(const fx4*)&bptr[nn0 + (2 * np + 1) * 16 + quad * 4];
                    fx4 ea = acc[mt][2 * np], eb = acc[mt][2 * np + 1];
                    #pragma unroll
                    for (int r = 0; r < 4; r++) {
                        ea[r] = (ea[r] + ba[r]) * scl;
                        eb[r] = (eb[r] + bb[r]) * scl;
                    }
                    uint4 pk = pack32(ea, eb);
                    *(uint4*)(crow + (np * 32 + quad * 8)) = pk;
                }
            }
        }
    } else {
        // MODE1 (swapped acc: n = nt*16+quad*4+r, m = mt*16+ln): fx4 stores,
        // bias folded per store (loads CSE'd across mt).
        int nbase = n0 + wn * (BN / 2);
        #pragma unroll
        for (int mt = 0; mt < MT; mt++) {
            int m = m0 + wm * (BM / 2) + mt * 16 + ln;
            #pragma unroll
            for (int nt = 0; nt < NT; nt++) {
                fx4 bo4 = *(const fx4*)&bo[nbase + nt * 16 + quad * 4];
                fx4 v = acc[mt][nt] + bo4;
                *(fx4*)&Cout[(size_t)m * 1024 + nbase + nt * 16 + quad * 4] = v;
            }
        }
    }
}

// ---------------- flash attention: 2x2 wave split (q x key), fused epilogue ----------------
// v5 (unchanged): wave (wq,wk) owns 32 q-rows x 32 keys; per-wave LDS reads
// data-minimal; key-partial O reduced across the wk pair in the epilogue;
// l = mfma(ones, P) on the matrix pipe; s_setprio(1) around MFMA clusters.
__global__ __launch_bounds__(256, 4) void flash_attn(
        const short* __restrict__ Q, const short* __restrict__ Kg,
        const short* __restrict__ Vt, short* __restrict__ Ctx) {
    // 32 KB: [K buf0 | K buf1 | V buf0 | V buf1], 4096 shorts each.
    // Epilogue reuse: floats [0,2176) per-wq transpose scratch,
    // [2176,6272) o-reduce (2 x 2048), [6272,6336) l-reduce.
    __shared__ __align__(16) short SH[16384];

    int tid = threadIdx.x;
    int w = tid >> 6, l = tid & 63, quad = l >> 4, ln = l & 15;
    int wq = w & 1, wk = w >> 1;
    // XCD-aware decode: 4 bh per XCD, 32 q-blocks per bh
    int id = blockIdx.x;
    int xcd = id & 7, local = id >> 3;           // local 0..127
    int bh = xcd * 4 + (local & 3);
    int qx = local >> 2;                         // 0..31
    int qblk = qx * 64 + wq * 32;                // this wave's 32 q-rows
    int b = bh >> 4, h = bh & 15;
    const short* Qb = Q  + (size_t)bh * 2048 * 64;
    const short* Kb = Kg + (size_t)bh * 2048 * 64;
    const short* Vb = Vt + (size_t)bh * 64 * 2048;
    int swz = ln & 7;

    // Q fragments (B-operand), 32 rows
    bh8 qf[2][2];
    #pragma unroll
    for (int qt = 0; qt < 2; qt++)
        #pragma unroll
        for (int c = 0; c < 2; c++)
            qf[qt][c] = *(const bh8*)&Qb[(size_t)(qblk + qt * 16 + ln) * 64 + c * 32 + quad * 8];

    // all-ones bf16 A-fragment for the l row-sum MFMA
    union { short s[8]; bh8 v; } one_;
    #pragma unroll
    for (int j = 0; j < 8; j++) one_.s[j] = 0x3F80;
    bh8 onesv = one_.v;

    // DMA staging map (block-cooperative, by raw wave id w): chunk c = w*2+j
    // covers tile rows [c*8, c*8+8). Linear LDS dest: lane l -> c*512 + l*8.
    // Global source pre-swizzled so LDS[row][p] holds col-group p^(row&7).
    const short* srcK[2]; const short* srcV[2]; int dstoff[2];
    #pragma unroll
    for (int j = 0; j < 2; j++) {
        int c = w * 2 + j;
        int row = c * 8 + (l >> 3);
        int pg = (l & 7) ^ (row & 7);
        srcK[j] = Kb + row * 64 + pg * 8;
        srcV[j] = Vb + (size_t)row * 2048 + pg * 8;
        dstoff[j] = c * 512;
    }

    // prologue: stage tile 0 into buf 0
    #pragma unroll
    for (int j = 0; j < 2; j++) {
        gload_lds16(srcK[j], SH + dstoff[j]);
        gload_lds16(srcV[j], SH + 8192 + dstoff[j]);
    }

    fx4 o[2][4] = {};
    fx4 lacc[2] = {};

    for (int it = 0; it < 32; ++it) {
        int koff = (it & 1) ? 4096 : 0;
        // tile `it` DMA complete + all waves done reading buf it^1.
        asm volatile("s_waitcnt vmcnt(0) lgkmcnt(0)\n\ts_barrier" ::: "memory");
        if (it < 31) {   // issue next-tile DMA into the other buffer; waited next iter
            int noff = koff ^ 4096;
            int kg = (it + 1) * 4096, vg = (it + 1) * 64;
            #pragma unroll
            for (int j = 0; j < 2; j++) {
                gload_lds16(srcK[j] + kg, SH + noff + dstoff[j]);
                gload_lds16(srcV[j] + vg, SH + 8192 + noff + dstoff[j]);
            }
        }
        const short* ksb = SH + koff;
        const short* vsb = SH + 8192 + koff;

        // S^T[key][q] = K * Q^T  (this wave: keys wk*32.., 32 q-cols)
        bh8 kf[2][2];
        #pragma unroll
        for (int mt = 0; mt < 2; mt++) {
            int krow = (wk * 32 + mt * 16 + ln) * 64;
            kf[mt][0] = *(const bh8*)&ksb[krow + ((quad ^ swz) * 8)];
            kf[mt][1] = *(const bh8*)&ksb[krow + (((quad + 4) ^ swz) * 8)];
        }
        fx4 s[2][2] = {};
        __builtin_amdgcn_s_setprio(1);
        #pragma unroll
        for (int mt = 0; mt < 2; mt++)
            #pragma unroll
            for (int qt = 0; qt < 2; qt++) {
                s[qt][mt] = __builtin_amdgcn_mfma_f32_16x16x32_bf16(kf[mt][0], qf[qt][0], s[qt][mt], 0, 0, 0);
                s[qt][mt] = __builtin_amdgcn_mfma_f32_16x16x32_bf16(kf[mt][1], qf[qt][1], s[qt][mt], 0, 0, 0);
            }
        __builtin_amdgcn_s_setprio(0);

        // P = exp2(S), packed to PV B-fragments entirely in-register
        bh8 pf[2];
        #pragma unroll
        for (int qt = 0; qt < 2; qt++) {
            fx4 e0, e1;
            #pragma unroll
            for (int r = 0; r < 4; r++) {
                e0[r] = __builtin_amdgcn_exp2f(s[qt][0][r]);
                e1[r] = __builtin_amdgcn_exp2f(s[qt][1][r]);
            }
            uint4 pk = pack32(e0, e1);
            union { uint4 u; bh8 v; } pc;
            pc.u = pk;
            pf[qt] = pc.v;
        }

        // O^T += V^T * P^T over this wave's 32 keys; l via ones-MFMA row-sum
        __builtin_amdgcn_s_setprio(1);
        #pragma unroll
        for (int dt = 0; dt < 4; dt++) {
            bh8 vf = *(const bh8*)&vsb[(dt * 16 + ln) * 64 + (((wk * 4 + quad) ^ swz) * 8)];
            o[0][dt] = __builtin_amdgcn_mfma_f32_16x16x32_bf16(vf, pf[0], o[0][dt], 0, 0, 0);
            o[1][dt] = __builtin_amdgcn_mfma_f32_16x16x32_bf16(vf, pf[1], o[1][dt], 0, 0, 0);
        }
        lacc[0] = __builtin_amdgcn_mfma_f32_16x16x32_bf16(onesv, pf[0], lacc[0], 0, 0, 0);
        lacc[1] = __builtin_amdgcn_mfma_f32_16x16x32_bf16(onesv, pf[1], lacc[1], 0, 0, 0);
        __builtin_amdgcn_s_setprio(0);
    }

    // all waves done reading K/V LDS before reusing it as epilogue scratch
    asm volatile("s_waitcnt vmcnt(0) lgkmcnt(0)\n\ts_barrier" ::: "memory");

    float* R  = (float*)SH + 2176;            // o-reduce: 2 regions x 2048 floats
    float* R2 = (float*)SH + 2176 + 4096;     // l-reduce: 2 x 32 floats

    // wk=1 waves publish their key-partial O and l
    if (wk == 1) {
        float* Rw = R + wq * 2048;
        #pragma unroll
        for (int qt = 0; qt < 2; qt++)
            #pragma unroll
            for (int dt = 0; dt < 4; dt++)
                *(fx4*)&Rw[(((qt * 4 + dt) * 4 + quad) * 16 + ln) * 4] = o[qt][dt];
        if (quad == 0) {
            R2[wq * 32 + 0 * 16 + ln] = lacc[0][0];
            R2[wq * 32 + 1 * 16 + ln] = lacc[1][0];
        }
    }
    asm volatile("s_waitcnt lgkmcnt(0)\n\ts_barrier" ::: "memory");

    if (wk == 0) {
        // reduce across the wk pair
        float* Rw = R + wq * 2048;
        float linv[2];
        #pragma unroll
        for (int qt = 0; qt < 2; qt++) {
            #pragma unroll
            for (int dt = 0; dt < 4; dt++)
                o[qt][dt] += *(const fx4*)&Rw[(((qt * 4 + dt) * 4 + quad) * 16 + ln) * 4];
            float lf = lacc[qt][0] + R2[wq * 32 + qt * 16 + ln];
            linv[qt] = 1.0f / lf;
        }
        // O^T -> rows via per-wave LDS transpose, scale by 1/l, bf16 out.
        float* PsF = (float*)SH + wq * 1088;   // 16 rows x 68-float stride
        int row = l >> 2, seg = l & 3;
        #pragma unroll
        for (int qt = 0; qt < 2; qt++) {
            #pragma unroll
            for (int dt = 0; dt < 4; dt++)
                *(fx4*)&PsF[ln * 68 + dt * 16 + quad * 4] = o[qt][dt];
            asm volatile("s_waitcnt lgkmcnt(0)" ::: "memory");
            float invr = __shfl(linv[qt], row);    // lane `row` holds l for q-row `row`
            int q = qblk + qt * 16 + row;
            short* crow = Ctx + ((size_t)(b * 2048 + q)) * 1024 + h * 64 + seg * 16;
            union { short s[8]; uint4 u; } o0, o1;
            #pragma unroll
            for (int j = 0; j < 2; j++) {
                fx4 v = *(const fx4*)&PsF[row * 68 + seg * 16 + j * 4];
                o0.s[j * 4 + 0] = f2bs(v[0] * invr);
                o0.s[j * 4 + 1] = f2bs(v[1] * invr);
                o0.s[j * 4 + 2] = f2bs(v[2] * invr);
                o0.s[j * 4 + 3] = f2bs(v[3] * invr);
            }
            #pragma unroll
            for (int j = 2; j < 4; j++) {
                fx4 v = *(const fx4*)&PsF[row * 68 + seg * 16 + j * 4];
                o1.s[(j - 2) * 4 + 0] = f2bs(v[0] * invr);
                o1.s[(j - 2) * 4 + 1] = f2bs(v[1] * invr);
                o1.s[(j - 2) * 4 + 2] = f2bs(v[2] * invr);
                o1.s[(j - 2) * 4 + 3] = f2bs(v[3] * invr);
            }
            *(uint4*)&crow[0] = o0.u;
            *(uint4*)&crow[8] = o1.u;
            asm volatile("s_waitcnt lgkmcnt(0)" ::: "memory");  // reads done before next qt overwrites
        }
    }
}

extern "C" void kernel_launch(void* const* d_in, const int* in_sizes, int n_in,
                              void* d_out, int out_size, void* d_ws, size_t ws_size,
                              hipStream_t stream) {
    const float* emb = (const float*)d_in[0];
    const float* Wq  = (const float*)d_in[1];
    const float* bq  = (const float*)d_in[2];
    const float* Wk  = (const float*)d_in[3];
    const float* bk  = (const float*)d_in[4];
    const float* Wv  = (const float*)d_in[5];
    const float* bv  = (const float*)d_in[6];
    const float* Wo  = (const float*)d_in[7];
    const float* bo  = (const float*)d_in[8];

    char* ws = (char*)d_ws;
    const size_t MB = 1024 * 1024;
    short* Xbf  = (short*)(ws + 0);          // A panel for QKV gemm
    short* Ctx  = (short*)(ws + 0);          // flash bf16 output (overlays Xbf,
                                             // which is dead after the QKV gemm)
    short* Wt   = (short*)(ws + 8 * MB);
    short* Wot  = (short*)(ws + 17 * MB);
    short* Qb   = (short*)(ws + 19 * MB);    // pre-scaled by QSCALE
    short* Kb   = (short*)(ws + 27 * MB);
    short* Vtb  = (short*)(ws + 35 * MB);    // [B,H,Dh,S]

    // fused prep: emb->bf16 (4096 blocks) + 4x weight transpose (1024 blocks)
    prep<<<5120, 256, 0, stream>>>(emb, Xbf, Wq, Wk, Wv, Wo, Wt, Wot);
    // QKV projection: 128x128 tiles, 32x24 = 768 blocks, XCD-swizzled
    gemm_bt_t<128, 128, NQKV, 0><<<768, 256, 0, stream>>>(
        Xbf, Wt, bq, bk, bv, nullptr, Qb, Kb, Vtb, nullptr);
    // attention: 1024 blocks = 4/CU, 64 q-rows each, 2x2 wave split, fused bf16 out
    flash_attn<<<1024, 256, 0, stream>>>(Qb, Kb, Vtb, Ctx);
    // output projection: 64x128 tiles, 64x8 = 512 blocks, XCD-swizzled
    gemm_bt_t<64, 128, DMODEL, 1><<<512, 256, 0, stream>>>(
        Ctx, Wot, nullptr, nullptr, nullptr, bo, nullptr, nullptr, nullptr, (float*)d_out);
}

// Round 11
// 194.877 us; speedup vs baseline: 1.0556x; 1.0272x over previous
//
#include <hip/hip_runtime.h>
#include <hip/hip_bf16.h>

// ---- problem constants ----
#define BB 2
#define SS 2048
#define DMODEL 1024
#define NHEADS 16
#define DHEAD 64
#define MTOT (BB*SS)      // 4096
#define NQKV 3072
#define QSCALE 0.18033688011112042f   // 0.125 * log2(e), folded into Q at projection

typedef short bh8 __attribute__((ext_vector_type(8)));   // 8 bf16 (4 VGPRs)
typedef float fx4 __attribute__((ext_vector_type(4)));   // MFMA accumulator
typedef unsigned int ux2 __attribute__((ext_vector_type(2)));

__device__ __forceinline__ short f2bs(float f) {
    __hip_bfloat16 h = __float2bfloat16(f);
    return *reinterpret_cast<short*>(&h);
}

__device__ __forceinline__ unsigned pk_bf16(float a, float b) {
    __hip_bfloat162 h = __float22bfloat162_rn(make_float2(a, b));
    return *reinterpret_cast<unsigned*>(&h);
}

// verified lane transform: inputs ea,eb = two row-tile fragments (reg axis =
// 4 consecutive rows at quad*4); output = uint4 whose 8 bf16 are 8 consecutive
// rows at quad*8 within the 32-row span, same column (ln). Axis-agnostic.
__device__ __forceinline__ uint4 pack32(fx4 ea, fx4 eb) {
    unsigned xa = pk_bf16(ea[0], ea[1]);
    unsigned ya = pk_bf16(ea[2], ea[3]);
    unsigned xb = pk_bf16(eb[0], eb[1]);
    unsigned yb = pk_bf16(eb[2], eb[3]);
    ux2 u   = __builtin_amdgcn_permlane32_swap(xa, xb, false, false);
    ux2 d02 = __builtin_amdgcn_permlane16_swap(u.x, u.y, false, false);
    ux2 u2  = __builtin_amdgcn_permlane32_swap(ya, yb, false, false);
    ux2 d13 = __builtin_amdgcn_permlane16_swap(u2.x, u2.y, false, false);
    uint4 r;
    r.x = d02.x; r.y = d13.x; r.z = d02.y; r.w = d13.y;
    return r;
}

// async global->LDS, 16B per lane. LDS dest wave-uniform base + lane*16.
__device__ __forceinline__ void gload_lds16(const short* g, short* l) {
    __builtin_amdgcn_global_load_lds(
        (const __attribute__((address_space(1))) unsigned int*)g,
        (__attribute__((address_space(3))) unsigned int*)l, 16, 0, 0);
}

// ---------------- prep: cvt emb (blocks 0..4095) + transpose weights (4096..5119) ----------------
__global__ __launch_bounds__(256) void prep(
        const float* __restrict__ emb, short* __restrict__ Xbf,
        const float* __restrict__ Wq, const float* __restrict__ Wk,
        const float* __restrict__ Wv, const float* __restrict__ Wo,
        short* __restrict__ Wt_qkv, short* __restrict__ Wot) {
    __shared__ float tile[64][65];
    int bid = blockIdx.x, tid = threadIdx.x;
    if (bid < 4096) {
        int i = (bid * 256 + tid) * 4;          // exactly covers MTOT*DMODEL
        float4 v = *(const float4*)(emb + i);
        short4 o;
        o.x = f2bs(v.x); o.y = f2bs(v.y); o.z = f2bs(v.z); o.w = f2bs(v.w);
        *(short4*)(Xbf + i) = o;
    } else {
        int b2 = bid - 4096;
        int bx = b2 & 15, by = (b2 >> 4) & 15, z = b2 >> 8;
        const float* src = (z == 0) ? Wq : (z == 1) ? Wk : (z == 2) ? Wv : Wo;
        short* dst = (z == 3) ? Wot : (Wt_qkv + (size_t)z * 1024 * 1024);
        int n0 = bx * 64, k0 = by * 64;
        int tx = tid & 63, ty = tid >> 6;
        for (int j = 0; j < 16; j++) {
            int r = ty + j * 4;
            tile[r][tx] = src[(size_t)(k0 + r) * 1024 + n0 + tx];
        }
        __syncthreads();
        // vectorized write-out: short4 per store (was 16x scalar 2B stores).
        // LDS read banks: 2-way aliasing only (free, m136).
        int c4 = tid & 15, rr = tid >> 4;
        #pragma unroll
        for (int pass = 0; pass < 4; pass++) {
            int r = rr + pass * 16;
            short4 o;
            o.x = f2bs(tile[c4 * 4 + 0][r]);
            o.y = f2bs(tile[c4 * 4 + 1][r]);
            o.z = f2bs(tile[c4 * 4 + 2][r]);
            o.w = f2bs(tile[c4 * 4 + 3][r]);
            *(short4*)&dst[(size_t)(n0 + r) * 1024 + k0 + c4 * 4] = o;
        }
    }
}

// ---------------- bt-GEMM (templated): C[m][n] = sum_k A[m][k]*Bt[n][k] ----------------
// BMxBN block, 4 waves (2x2), 3-stage global_load_lds pipeline with raw
// s_waitcnt vmcnt(CPW)+s_barrier (never vmcnt(0) mid-loop). XCD-aware 1D grid.
// v9 (unchanged, verified in round 9): __launch_bounds__(256,4) caps VGPR at
// 128 (the 136-VGPR cliff in v8 cost 8 µs); register-lean epilogues with bias
// folded into the pack/store loops.
template<int BM, int BN, int NN, int MODE>
__global__ __launch_bounds__(256, 4) void gemm_bt_t(
        const short* __restrict__ A, const short* __restrict__ Bt,
        const float* __restrict__ bq, const float* __restrict__ bk,
        const float* __restrict__ bv, const float* __restrict__ bo,
        short* __restrict__ Qout, short* __restrict__ Kout,
        short* __restrict__ Vtout, float* __restrict__ Cout) {
    const int K = 1024;
    constexpr int ROWS = BM + BN;        // combined A+B panel rows per k-tile
    constexpr int CPW  = ROWS / 64;      // 16-row staging chunks per wave
    constexpr int MBK  = MTOT / BM;      // m-blocks
    constexpr int STRIP = MBK / 8;       // m-tiles per XCD strip
    constexpr int MT = BM / 32, NT = BN / 32;
    __shared__ __align__(16) short S[3][ROWS * 32];

    int tid = threadIdx.x;
    int w = tid >> 6, l = tid & 63, quad = l >> 4, ln = l & 15;
    int wm = w & 1, wn = w >> 1;

    // XCD-aware decode: id%8 ~ XCD; XCD owns M-strip [xcd*STRIP, xcd*STRIP+STRIP)
    int id = blockIdx.x;
    int xcd = id & 7, local = id >> 3;
    int mi = xcd * STRIP + (local % STRIP);
    int ni = local / STRIP;
    int m0 = mi * BM, n0 = ni * BN;

    // block-uniform output kind (MODE 0): 0=Q 1=K 2=V
    const int which = (MODE == 0) ? (n0 >> 10) : 2;
    // swapped MFMA operands everywhere except the MODE0 V path
    const bool swp = (MODE == 1) || (which != 2);

    // staging chunk map: chunk c = w*CPW+j covers panel rows [c*16, c*16+16);
    // panel rows [0,BM) = A tile rows, [BM,ROWS) = B tile rows.
    const short* gsrc[CPW];
    int loff[CPW];
    #pragma unroll
    for (int j = 0; j < CPW; j++) {
        int r0 = (w * CPW + j) * 16;
        int row = r0 + (l >> 2);
        gsrc[j] = (r0 < BM ? A + (size_t)(m0 + row) * K
                           : Bt + (size_t)(n0 + row - BM) * K) + (l & 3) * 8;
        loff[j] = r0 * 32;
    }

    short *sC = &S[0][0], *sN = &S[1][0], *sN2 = &S[2][0];
    #pragma unroll
    for (int j = 0; j < CPW; j++) gload_lds16(gsrc[j], sC + loff[j]);
    #pragma unroll
    for (int j = 0; j < CPW; j++) gload_lds16(gsrc[j] + 32, sN + loff[j]);

    fx4 acc[MT][NT] = {};
    for (int it = 0; it < 32; ++it) {
        if (it < 31) {
            if constexpr (CPW == 4)
                asm volatile("s_waitcnt vmcnt(4)\n\ts_barrier" ::: "memory");
            else
                asm volatile("s_waitcnt vmcnt(3)\n\ts_barrier" ::: "memory");
        } else {
            asm volatile("s_waitcnt vmcnt(0)\n\ts_barrier" ::: "memory");
        }
        if (it < 30) {
            int k0 = (it + 2) * 32;
            #pragma unroll
            for (int j = 0; j < CPW; j++) gload_lds16(gsrc[j] + k0, sN2 + loff[j]);
        }
        bh8 af[MT], bf[NT];
        #pragma unroll
        for (int mt = 0; mt < MT; mt++)
            af[mt] = *(const bh8*)&sC[(wm * (BM / 2) + mt * 16 + ln) * 32 + quad * 8];
        #pragma unroll
        for (int nt = 0; nt < NT; nt++)
            bf[nt] = *(const bh8*)&sC[(BM + wn * (BN / 2) + nt * 16 + ln) * 32 + quad * 8];
        if (!swp) {
            #pragma unroll
            for (int mt = 0; mt < MT; mt++)
                #pragma unroll
                for (int nt = 0; nt < NT; nt++)
                    acc[mt][nt] = __builtin_amdgcn_mfma_f32_16x16x32_bf16(af[mt], bf[nt], acc[mt][nt], 0, 0, 0);
        } else {
            // swapped: C row axis = n, col axis = m
            #pragma unroll
            for (int mt = 0; mt < MT; mt++)
                #pragma unroll
                for (int nt = 0; nt < NT; nt++)
                    acc[mt][nt] = __builtin_amdgcn_mfma_f32_16x16x32_bf16(bf[nt], af[mt], acc[mt][nt], 0, 0, 0);
        }
        short* t;
        t = sC; sC = sN; sN = sN2; sN2 = t;
    }

    if constexpr (MODE == 0) {
        int nbase = n0 + wn * 64;
        int nn0 = nbase & 1023;          // multiple of 64 (this wave's 64-d base)
        int h = nn0 >> 6;
        int mbase_w = m0 + wm * 64;      // 64-aligned, never crosses batch
        int bb_ = mbase_w >> 11, s0 = mbase_w & 2047;

        if (which == 2) {
            // V (non-swapped acc: row=m, col=d=nt*16+ln). Bias folded into the
            // pack loop (lane-scalar per nt); pack32 over mt-pairs -> 8
            // consecutive s at fixed d; 16B stores.
            #pragma unroll
            for (int nt = 0; nt < NT; nt++) {
                float bias = bv[nn0 + nt * 16 + ln];
                fx4 bb4 = {bias, bias, bias, bias};
                int d = nt * 16 + ln;
                short* vrow = Vtout + ((size_t)(bb_ * 16 + h) * 64 + d) * 2048 + s0;
                #pragma unroll
                for (int mp = 0; mp < MT / 2; mp++) {
                    uint4 pk = pack32(acc[2 * mp][nt] + bb4, acc[2 * mp + 1][nt] + bb4);
                    *(uint4*)(vrow + (mp * 32 + quad * 8)) = pk;
                }
            }
        } else {
            // Q/K (swapped acc: d = nt*16+quad*4+r, s = mt*16+ln). Bias+scale
            // folded into the pack loop (fx4 loads, CSE'd across mt); pack32
            // over nt-pairs -> 8 consecutive d at fixed s; 16B [s][d] stores.
            const float* bptr = (which == 0) ? bq : bk;
            float scl = (which == 0) ? QSCALE : 1.0f;
            short* out = (which == 0) ? Qout : Kout;
            #pragma unroll
            for (int mt = 0; mt < MT; mt++) {
                int s_ = s0 + mt * 16 + ln;
                short* crow = out + (((size_t)(bb_ * 16 + h) * 2048) + s_) * 64;
                #pragma unroll
                for (int np = 0; np < NT / 2; np++) {
                    fx4 ba = *(const fx4*)&bptr[nn0 + (2 * np) * 16 + quad * 4];
                    fx4 bb = *(const fx4*)&bptr[nn0 + (2 * np + 1) * 16 + quad * 4];
                    fx4 ea = acc[mt][2 * np], eb = acc[mt][2 * np + 1];
                    #pragma unroll
                    for (int r = 0; r < 4; r++) {
                        ea[r] = (ea[r] + ba[r]) * scl;
                        eb[r] = (eb[r] + bb[r]) * scl;
                    }
                    uint4 pk = pack32(ea, eb);
                    *(uint4*)(crow + (np * 32 + quad * 8)) = pk;
                }
            }
        }
    } else {
        // MODE1 (swapped acc: n = nt*16+quad*4+r, m = mt*16+ln): fx4 stores,
        // bias folded per store (loads CSE'd across mt).
        int nbase = n0 + wn * (BN / 2);
        #pragma unroll
        for (int mt = 0; mt < MT; mt++) {
            int m = m0 + wm * (BM / 2) + mt * 16 + ln;
            #pragma unroll
            for (int nt = 0; nt < NT; nt++) {
                fx4 bo4 = *(const fx4*)&bo[nbase + nt * 16 + quad * 4];
                fx4 v = acc[mt][nt] + bo4;
                *(fx4*)&Cout[(size_t)m * 1024 + nbase + nt * 16 + quad * 4] = v;
            }
        }
    }
}

// ---------------- flash attention: 2x2 wave split (q x key), fused epilogue ----------------
// v6: v5 + explicit V-fragment prefetch. The 4 vf reads depend only on the
// staged buffer (valid since the top barrier), NOT on QK/softmax — issuing
// them right after the kf reads takes the ~120-180cy LDS latency off the
// per-iteration serial chain (paid 32x). Compiler's counted lgkmcnt lets the
// QK MFMAs wait only on the 4 kf returns.
__global__ __launch_bounds__(256, 4) void flash_attn(
        const short* __restrict__ Q, const short* __restrict__ Kg,
        const short* __restrict__ Vt, short* __restrict__ Ctx) {
    // 32 KB: [K buf0 | K buf1 | V buf0 | V buf1], 4096 shorts each.
    // Epilogue reuse: floats [0,2176) per-wq transpose scratch,
    // [2176,6272) o-reduce (2 x 2048), [6272,6336) l-reduce.
    __shared__ __align__(16) short SH[16384];

    int tid = threadIdx.x;
    int w = tid >> 6, l = tid & 63, quad = l >> 4, ln = l & 15;
    int wq = w & 1, wk = w >> 1;
    // XCD-aware decode: 4 bh per XCD, 32 q-blocks per bh
    int id = blockIdx.x;
    int xcd = id & 7, local = id >> 3;           // local 0..127
    int bh = xcd * 4 + (local & 3);
    int qx = local >> 2;                         // 0..31
    int qblk = qx * 64 + wq * 32;                // this wave's 32 q-rows
    int b = bh >> 4, h = bh & 15;
    const short* Qb = Q  + (size_t)bh * 2048 * 64;
    const short* Kb = Kg + (size_t)bh * 2048 * 64;
    const short* Vb = Vt + (size_t)bh * 64 * 2048;
    int swz = ln & 7;

    // Q fragments (B-operand), 32 rows
    bh8 qf[2][2];
    #pragma unroll
    for (int qt = 0; qt < 2; qt++)
        #pragma unroll
        for (int c = 0; c < 2; c++)
            qf[qt][c] = *(const bh8*)&Qb[(size_t)(qblk + qt * 16 + ln) * 64 + c * 32 + quad * 8];

    // all-ones bf16 A-fragment for the l row-sum MFMA
    union { short s[8]; bh8 v; } one_;
    #pragma unroll
    for (int j = 0; j < 8; j++) one_.s[j] = 0x3F80;
    bh8 onesv = one_.v;

    // DMA staging map (block-cooperative, by raw wave id w): chunk c = w*2+j
    // covers tile rows [c*8, c*8+8). Linear LDS dest: lane l -> c*512 + l*8.
    // Global source pre-swizzled so LDS[row][p] holds col-group p^(row&7).
    const short* srcK[2]; const short* srcV[2]; int dstoff[2];
    #pragma unroll
    for (int j = 0; j < 2; j++) {
        int c = w * 2 + j;
        int row = c * 8 + (l >> 3);
        int pg = (l & 7) ^ (row & 7);
        srcK[j] = Kb + row * 64 + pg * 8;
        srcV[j] = Vb + (size_t)row * 2048 + pg * 8;
        dstoff[j] = c * 512;
    }

    // prologue: stage tile 0 into buf 0
    #pragma unroll
    for (int j = 0; j < 2; j++) {
        gload_lds16(srcK[j], SH + dstoff[j]);
        gload_lds16(srcV[j], SH + 8192 + dstoff[j]);
    }

    fx4 o[2][4] = {};
    fx4 lacc[2] = {};

    for (int it = 0; it < 32; ++it) {
        int koff = (it & 1) ? 4096 : 0;
        // tile `it` DMA complete + all waves done reading buf it^1.
        asm volatile("s_waitcnt vmcnt(0) lgkmcnt(0)\n\ts_barrier" ::: "memory");
        if (it < 31) {   // issue next-tile DMA into the other buffer; waited next iter
            int noff = koff ^ 4096;
            int kg = (it + 1) * 4096, vg = (it + 1) * 64;
            #pragma unroll
            for (int j = 0; j < 2; j++) {
                gload_lds16(srcK[j] + kg, SH + noff + dstoff[j]);
                gload_lds16(srcV[j] + vg, SH + 8192 + noff + dstoff[j]);
            }
        }
        const short* ksb = SH + koff;
        const short* vsb = SH + 8192 + koff;

        // Issue ALL LDS reads up front: kf for QK^T, then vf for PV (vf is
        // independent of QK results — explicit ILP so PV's V-read latency
        // overlaps the QK MFMA + softmax phases).
        bh8 kf[2][2];
        #pragma unroll
        for (int mt = 0; mt < 2; mt++) {
            int krow = (wk * 32 + mt * 16 + ln) * 64;
            kf[mt][0] = *(const bh8*)&ksb[krow + ((quad ^ swz) * 8)];
            kf[mt][1] = *(const bh8*)&ksb[krow + (((quad + 4) ^ swz) * 8)];
        }
        bh8 vf[4];
        #pragma unroll
        for (int dt = 0; dt < 4; dt++)
            vf[dt] = *(const bh8*)&vsb[(dt * 16 + ln) * 64 + (((wk * 4 + quad) ^ swz) * 8)];

        // S^T[key][q] = K * Q^T  (this wave: keys wk*32.., 32 q-cols)
        fx4 s[2][2] = {};
        __builtin_amdgcn_s_setprio(1);
        #pragma unroll
        for (int mt = 0; mt < 2; mt++)
            #pragma unroll
            for (int qt = 0; qt < 2; qt++) {
                s[qt][mt] = __builtin_amdgcn_mfma_f32_16x16x32_bf16(kf[mt][0], qf[qt][0], s[qt][mt], 0, 0, 0);
                s[qt][mt] = __builtin_amdgcn_mfma_f32_16x16x32_bf16(kf[mt][1], qf[qt][1], s[qt][mt], 0, 0, 0);
            }
        __builtin_amdgcn_s_setprio(0);

        // P = exp2(S), packed to PV B-fragments entirely in-register
        bh8 pf[2];
        #pragma unroll
        for (int qt = 0; qt < 2; qt++) {
            fx4 e0, e1;
            #pragma unroll
            for (int r = 0; r < 4; r++) {
                e0[r] = __builtin_amdgcn_exp2f(s[qt][0][r]);
                e1[r] = __builtin_amdgcn_exp2f(s[qt][1][r]);
            }
            uint4 pk = pack32(e0, e1);
            union { uint4 u; bh8 v; } pc;
            pc.u = pk;
            pf[qt] = pc.v;
        }

        // O^T += V^T * P^T over this wave's 32 keys; l via ones-MFMA row-sum
        __builtin_amdgcn_s_setprio(1);
        #pragma unroll
        for (int dt = 0; dt < 4; dt++) {
            o[0][dt] = __builtin_amdgcn_mfma_f32_16x16x32_bf16(vf[dt], pf[0], o[0][dt], 0, 0, 0);
            o[1][dt] = __builtin_amdgcn_mfma_f32_16x16x32_bf16(vf[dt], pf[1], o[1][dt], 0, 0, 0);
        }
        lacc[0] = __builtin_amdgcn_mfma_f32_16x16x32_bf16(onesv, pf[0], lacc[0], 0, 0, 0);
        lacc[1] = __builtin_amdgcn_mfma_f32_16x16x32_bf16(onesv, pf[1], lacc[1], 0, 0, 0);
        __builtin_amdgcn_s_setprio(0);
    }

    // all waves done reading K/V LDS before reusing it as epilogue scratch
    asm volatile("s_waitcnt vmcnt(0) lgkmcnt(0)\n\ts_barrier" ::: "memory");

    float* R  = (float*)SH + 2176;            // o-reduce: 2 regions x 2048 floats
    float* R2 = (float*)SH + 2176 + 4096;     // l-reduce: 2 x 32 floats

    // wk=1 waves publish their key-partial O and l
    if (wk == 1) {
        float* Rw = R + wq * 2048;
        #pragma unroll
        for (int qt = 0; qt < 2; qt++)
            #pragma unroll
            for (int dt = 0; dt < 4; dt++)
                *(fx4*)&Rw[(((qt * 4 + dt) * 4 + quad) * 16 + ln) * 4] = o[qt][dt];
        if (quad == 0) {
            R2[wq * 32 + 0 * 16 + ln] = lacc[0][0];
            R2[wq * 32 + 1 * 16 + ln] = lacc[1][0];
        }
    }
    asm volatile("s_waitcnt lgkmcnt(0)\n\ts_barrier" ::: "memory");

    if (wk == 0) {
        // reduce across the wk pair
        float* Rw = R + wq * 2048;
        float linv[2];
        #pragma unroll
        for (int qt = 0; qt < 2; qt++) {
            #pragma unroll
            for (int dt = 0; dt < 4; dt++)
                o[qt][dt] += *(const fx4*)&Rw[(((qt * 4 + dt) * 4 + quad) * 16 + ln) * 4];
            float lf = lacc[qt][0] + R2[wq * 32 + qt * 16 + ln];
            linv[qt] = 1.0f / lf;
        }
        // O^T -> rows via per-wave LDS transpose, scale by 1/l, bf16 out.
        float* PsF = (float*)SH + wq * 1088;   // 16 rows x 68-float stride
        int row = l >> 2, seg = l & 3;
        #pragma unroll
        for (int qt = 0; qt < 2; qt++) {
            #pragma unroll
            for (int dt = 0; dt < 4; dt++)
                *(fx4*)&PsF[ln * 68 + dt * 16 + quad * 4] = o[qt][dt];
            asm volatile("s_waitcnt lgkmcnt(0)" ::: "memory");
            float invr = __shfl(linv[qt], row);    // lane `row` holds l for q-row `row`
            int q = qblk + qt * 16 + row;
            short* crow = Ctx + ((size_t)(b * 2048 + q)) * 1024 + h * 64 + seg * 16;
            union { short s[8]; uint4 u; } o0, o1;
            #pragma unroll
            for (int j = 0; j < 2; j++) {
                fx4 v = *(const fx4*)&PsF[row * 68 + seg * 16 + j * 4];
                o0.s[j * 4 + 0] = f2bs(v[0] * invr);
                o0.s[j * 4 + 1] = f2bs(v[1] * invr);
                o0.s[j * 4 + 2] = f2bs(v[2] * invr);
                o0.s[j * 4 + 3] = f2bs(v[3] * invr);
            }
            #pragma unroll
            for (int j = 2; j < 4; j++) {
                fx4 v = *(const fx4*)&PsF[row * 68 + seg * 16 + j * 4];
                o1.s[(j - 2) * 4 + 0] = f2bs(v[0] * invr);
                o1.s[(j - 2) * 4 + 1] = f2bs(v[1] * invr);
                o1.s[(j - 2) * 4 + 2] = f2bs(v[2] * invr);
                o1.s[(j - 2) * 4 + 3] = f2bs(v[3] * invr);
            }
            *(uint4*)&crow[0] = o0.u;
            *(uint4*)&crow[8] = o1.u;
            asm volatile("s_waitcnt lgkmcnt(0)" ::: "memory");  // reads done before next qt overwrites
        }
    }
}

extern "C" void kernel_launch(void* const* d_in, const int* in_sizes, int n_in,
                              void* d_out, int out_size, void* d_ws, size_t ws_size,
                              hipStream_t stream) {
    const float* emb = (const float*)d_in[0];
    const float* Wq  = (const float*)d_in[1];
    const float* bq  = (const float*)d_in[2];
    const float* Wk  = (const float*)d_in[3];
    const float* bk  = (const float*)d_in[4];
    const float* Wv  = (const float*)d_in[5];
    const float* bv  = (const float*)d_in[6];
    const float* Wo  = (const float*)d_in[7];
    const float* bo  = (const float*)d_in[8];

    char* ws = (char*)d_ws;
    const size_t MB = 1024 * 1024;
    short* Xbf  = (short*)(ws + 0);          // A panel for QKV gemm
    short* Ctx  = (short*)(ws + 0);          // flash bf16 output (overlays Xbf,
                                             // which is dead after the QKV gemm)
    short* Wt   = (short*)(ws + 8 * MB);
    short* Wot  = (short*)(ws + 17 * MB);
    short* Qb   = (short*)(ws + 19 * MB);    // pre-scaled by QSCALE
    short* Kb   = (short*)(ws + 27 * MB);
    short* Vtb  = (short*)(ws + 35 * MB);    // [B,H,Dh,S]

    // fused prep: emb->bf16 (4096 blocks) + 4x weight transpose (1024 blocks)
    prep<<<5120, 256, 0, stream>>>(emb, Xbf, Wq, Wk, Wv, Wo, Wt, Wot);
    // QKV projection: 128x128 tiles, 32x24 = 768 blocks, XCD-swizzled
    gemm_bt_t<128, 128, NQKV, 0><<<768, 256, 0, stream>>>(
        Xbf, Wt, bq, bk, bv, nullptr, Qb, Kb, Vtb, nullptr);
    // attention: 1024 blocks = 4/CU, 64 q-rows each, 2x2 wave split, fused bf16 out
    flash_attn<<<1024, 256, 0, stream>>>(Qb, Kb, Vtb, Ctx);
    // output projection: 64x128 tiles, 64x8 = 512 blocks, XCD-swizzled
    gemm_bt_t<64, 128, DMODEL, 1><<<512, 256, 0, stream>>>(
        Ctx, Wot, nullptr, nullptr, nullptr, bo, nullptr, nullptr, nullptr, (float*)d_out);
}

// Round 12
// 192.759 us; speedup vs baseline: 1.0672x; 1.0110x over previous
//
#include <hip/hip_runtime.h>
#include <hip/hip_bf16.h>

// ---- problem constants ----
#define BB 2
#define SS 2048
#define DMODEL 1024
#define NHEADS 16
#define DHEAD 64
#define MTOT (BB*SS)      // 4096
#define NQKV 3072
#define QSCALE 0.18033688011112042f   // 0.125 * log2(e), folded into Q at projection

typedef short bh8 __attribute__((ext_vector_type(8)));   // 8 bf16 (4 VGPRs)
typedef float fx4 __attribute__((ext_vector_type(4)));   // MFMA accumulator
typedef unsigned int ux2 __attribute__((ext_vector_type(2)));

__device__ __forceinline__ short f2bs(float f) {
    __hip_bfloat16 h = __float2bfloat16(f);
    return *reinterpret_cast<short*>(&h);
}

__device__ __forceinline__ unsigned pk_bf16(float a, float b) {
    __hip_bfloat162 h = __float22bfloat162_rn(make_float2(a, b));
    return *reinterpret_cast<unsigned*>(&h);
}

// verified lane transform: inputs ea,eb = two row-tile fragments (reg axis =
// 4 consecutive rows at quad*4); output = uint4 whose 8 bf16 are 8 consecutive
// rows at quad*8 within the 32-row span, same column (ln). Axis-agnostic.
__device__ __forceinline__ uint4 pack32(fx4 ea, fx4 eb) {
    unsigned xa = pk_bf16(ea[0], ea[1]);
    unsigned ya = pk_bf16(ea[2], ea[3]);
    unsigned xb = pk_bf16(eb[0], eb[1]);
    unsigned yb = pk_bf16(eb[2], eb[3]);
    ux2 u   = __builtin_amdgcn_permlane32_swap(xa, xb, false, false);
    ux2 d02 = __builtin_amdgcn_permlane16_swap(u.x, u.y, false, false);
    ux2 u2  = __builtin_amdgcn_permlane32_swap(ya, yb, false, false);
    ux2 d13 = __builtin_amdgcn_permlane16_swap(u2.x, u2.y, false, false);
    uint4 r;
    r.x = d02.x; r.y = d13.x; r.z = d02.y; r.w = d13.y;
    return r;
}

// async global->LDS, 16B per lane. LDS dest wave-uniform base + lane*16.
__device__ __forceinline__ void gload_lds16(const short* g, short* l) {
    __builtin_amdgcn_global_load_lds(
        (const __attribute__((address_space(1))) unsigned int*)g,
        (__attribute__((address_space(3))) unsigned int*)l, 16, 0, 0);
}

// ---------------- prep: cvt emb (blocks 0..4095) + transpose weights (4096..5119) ----------------
__global__ __launch_bounds__(256) void prep(
        const float* __restrict__ emb, short* __restrict__ Xbf,
        const float* __restrict__ Wq, const float* __restrict__ Wk,
        const float* __restrict__ Wv, const float* __restrict__ Wo,
        short* __restrict__ Wt_qkv, short* __restrict__ Wot) {
    __shared__ float tile[64][65];
    int bid = blockIdx.x, tid = threadIdx.x;
    if (bid < 4096) {
        int i = (bid * 256 + tid) * 4;          // exactly covers MTOT*DMODEL
        float4 v = *(const float4*)(emb + i);
        short4 o;
        o.x = f2bs(v.x); o.y = f2bs(v.y); o.z = f2bs(v.z); o.w = f2bs(v.w);
        *(short4*)(Xbf + i) = o;
    } else {
        int b2 = bid - 4096;
        int bx = b2 & 15, by = (b2 >> 4) & 15, z = b2 >> 8;
        const float* src = (z == 0) ? Wq : (z == 1) ? Wk : (z == 2) ? Wv : Wo;
        short* dst = (z == 3) ? Wot : (Wt_qkv + (size_t)z * 1024 * 1024);
        int n0 = bx * 64, k0 = by * 64;
        int tx = tid & 63, ty = tid >> 6;
        for (int j = 0; j < 16; j++) {
            int r = ty + j * 4;
            tile[r][tx] = src[(size_t)(k0 + r) * 1024 + n0 + tx];
        }
        __syncthreads();
        // vectorized write-out: short4 per store (was 16x scalar 2B stores).
        // LDS read banks: 2-way aliasing only (free, m136).
        int c4 = tid & 15, rr = tid >> 4;
        #pragma unroll
        for (int pass = 0; pass < 4; pass++) {
            int r = rr + pass * 16;
            short4 o;
            o.x = f2bs(tile[c4 * 4 + 0][r]);
            o.y = f2bs(tile[c4 * 4 + 1][r]);
            o.z = f2bs(tile[c4 * 4 + 2][r]);
            o.w = f2bs(tile[c4 * 4 + 3][r]);
            *(short4*)&dst[(size_t)(n0 + r) * 1024 + k0 + c4 * 4] = o;
        }
    }
}

// ---------------- bt-GEMM (templated): C[m][n] = sum_k A[m][k]*Bt[n][k] ----------------
// BMxBN block, 4 waves (2x2), 3-stage global_load_lds pipeline with raw
// s_waitcnt vmcnt(CPW)+s_barrier (never vmcnt(0) mid-loop). XCD-aware 1D grid.
// v10: out-proj moved to 64x64 tiles -> 1024 blocks = 4 blocks/CU (was 64x128,
// 512 blocks = 2/CU = 2 waves/SIMD, grid-starved — the ~40µs "sleeper" hiding
// under the top-5 cutoff). Counted-vmcnt literal generalized for CPW=2
// (prologue 4 outstanding; wait vmcnt(2) keeps next tile's 2 loads in flight;
// vmcnt(3) would NOT guarantee tile-it complete).
template<int BM, int BN, int NN, int MODE>
__global__ __launch_bounds__(256, 4) void gemm_bt_t(
        const short* __restrict__ A, const short* __restrict__ Bt,
        const float* __restrict__ bq, const float* __restrict__ bk,
        const float* __restrict__ bv, const float* __restrict__ bo,
        short* __restrict__ Qout, short* __restrict__ Kout,
        short* __restrict__ Vtout, float* __restrict__ Cout) {
    const int K = 1024;
    constexpr int ROWS = BM + BN;        // combined A+B panel rows per k-tile
    constexpr int CPW  = ROWS / 64;      // 16-row staging chunks per wave
    constexpr int MBK  = MTOT / BM;      // m-blocks
    constexpr int STRIP = MBK / 8;       // m-tiles per XCD strip
    constexpr int MT = BM / 32, NT = BN / 32;
    __shared__ __align__(16) short S[3][ROWS * 32];

    int tid = threadIdx.x;
    int w = tid >> 6, l = tid & 63, quad = l >> 4, ln = l & 15;
    int wm = w & 1, wn = w >> 1;

    // XCD-aware decode: id%8 ~ XCD; XCD owns M-strip [xcd*STRIP, xcd*STRIP+STRIP)
    int id = blockIdx.x;
    int xcd = id & 7, local = id >> 3;
    int mi = xcd * STRIP + (local % STRIP);
    int ni = local / STRIP;
    int m0 = mi * BM, n0 = ni * BN;

    // block-uniform output kind (MODE 0): 0=Q 1=K 2=V
    const int which = (MODE == 0) ? (n0 >> 10) : 2;
    // swapped MFMA operands everywhere except the MODE0 V path
    const bool swp = (MODE == 1) || (which != 2);

    // staging chunk map: chunk c = w*CPW+j covers panel rows [c*16, c*16+16);
    // panel rows [0,BM) = A tile rows, [BM,ROWS) = B tile rows.
    const short* gsrc[CPW];
    int loff[CPW];
    #pragma unroll
    for (int j = 0; j < CPW; j++) {
        int r0 = (w * CPW + j) * 16;
        int row = r0 + (l >> 2);
        gsrc[j] = (r0 < BM ? A + (size_t)(m0 + row) * K
                           : Bt + (size_t)(n0 + row - BM) * K) + (l & 3) * 8;
        loff[j] = r0 * 32;
    }

    short *sC = &S[0][0], *sN = &S[1][0], *sN2 = &S[2][0];
    #pragma unroll
    for (int j = 0; j < CPW; j++) gload_lds16(gsrc[j], sC + loff[j]);
    #pragma unroll
    for (int j = 0; j < CPW; j++) gload_lds16(gsrc[j] + 32, sN + loff[j]);

    fx4 acc[MT][NT] = {};
    for (int it = 0; it < 32; ++it) {
        if (it < 31) {
            // counted wait: tile-it's CPW loads retired, next tile's stay in flight
            if constexpr (CPW == 4)
                asm volatile("s_waitcnt vmcnt(4)\n\ts_barrier" ::: "memory");
            else if constexpr (CPW == 3)
                asm volatile("s_waitcnt vmcnt(3)\n\ts_barrier" ::: "memory");
            else
                asm volatile("s_waitcnt vmcnt(2)\n\ts_barrier" ::: "memory");
        } else {
            asm volatile("s_waitcnt vmcnt(0)\n\ts_barrier" ::: "memory");
        }
        if (it < 30) {
            int k0 = (it + 2) * 32;
            #pragma unroll
            for (int j = 0; j < CPW; j++) gload_lds16(gsrc[j] + k0, sN2 + loff[j]);
        }
        bh8 af[MT], bf[NT];
        #pragma unroll
        for (int mt = 0; mt < MT; mt++)
            af[mt] = *(const bh8*)&sC[(wm * (BM / 2) + mt * 16 + ln) * 32 + quad * 8];
        #pragma unroll
        for (int nt = 0; nt < NT; nt++)
            bf[nt] = *(const bh8*)&sC[(BM + wn * (BN / 2) + nt * 16 + ln) * 32 + quad * 8];
        if (!swp) {
            #pragma unroll
            for (int mt = 0; mt < MT; mt++)
                #pragma unroll
                for (int nt = 0; nt < NT; nt++)
                    acc[mt][nt] = __builtin_amdgcn_mfma_f32_16x16x32_bf16(af[mt], bf[nt], acc[mt][nt], 0, 0, 0);
        } else {
            // swapped: C row axis = n, col axis = m
            #pragma unroll
            for (int mt = 0; mt < MT; mt++)
                #pragma unroll
                for (int nt = 0; nt < NT; nt++)
                    acc[mt][nt] = __builtin_amdgcn_mfma_f32_16x16x32_bf16(bf[nt], af[mt], acc[mt][nt], 0, 0, 0);
        }
        short* t;
        t = sC; sC = sN; sN = sN2; sN2 = t;
    }

    if constexpr (MODE == 0) {
        int nbase = n0 + wn * 64;
        int nn0 = nbase & 1023;          // multiple of 64 (this wave's 64-d base)
        int h = nn0 >> 6;
        int mbase_w = m0 + wm * 64;      // 64-aligned, never crosses batch
        int bb_ = mbase_w >> 11, s0 = mbase_w & 2047;

        if (which == 2) {
            // V (non-swapped acc: row=m, col=d=nt*16+ln). Bias folded into the
            // pack loop (lane-scalar per nt); pack32 over mt-pairs -> 8
            // consecutive s at fixed d; 16B stores.
            #pragma unroll
            for (int nt = 0; nt < NT; nt++) {
                float bias = bv[nn0 + nt * 16 + ln];
                fx4 bb4 = {bias, bias, bias, bias};
                int d = nt * 16 + ln;
                short* vrow = Vtout + ((size_t)(bb_ * 16 + h) * 64 + d) * 2048 + s0;
                #pragma unroll
                for (int mp = 0; mp < MT / 2; mp++) {
                    uint4 pk = pack32(acc[2 * mp][nt] + bb4, acc[2 * mp + 1][nt] + bb4);
                    *(uint4*)(vrow + (mp * 32 + quad * 8)) = pk;
                }
            }
        } else {
            // Q/K (swapped acc: d = nt*16+quad*4+r, s = mt*16+ln). Bias+scale
            // folded into the pack loop (fx4 loads, CSE'd across mt); pack32
            // over nt-pairs -> lane holds 8 consecutive d at fixed s; 16B stores.
            const float* bptr = (which == 0) ? bq : bk;
            float scl = (which == 0) ? QSCALE : 1.0f;
            short* out = (which == 0) ? Qout : Kout;
            #pragma unroll
            for (int mt = 0; mt < MT; mt++) {
                int s_ = s0 + mt * 16 + ln;
                short* crow = out + (((size_t)(bb_ * 16 + h) * 2048) + s_) * 64;
                #pragma unroll
                for (int np = 0; np < NT / 2; np++) {
                    fx4 ba = *(const fx4*)&bptr[nn0 + (2 * np) * 16 + quad * 4];
                    fx4 bb = *(const fx4*)&bptr[nn0 + (2 * np + 1) * 16 + quad * 4];
                    fx4 ea = acc[mt][2 * np], eb = acc[mt][2 * np + 1];
                    #pragma unroll
                    for (int r = 0; r < 4; r++) {
                        ea[r] = (ea[r] + ba[r]) * scl;
                        eb[r] = (eb[r] + bb[r]) * scl;
                    }
                    uint4 pk = pack32(ea, eb);
                    *(uint4*)(crow + (np * 32 + quad * 8)) = pk;
                }
            }
        }
    } else {
        // MODE1 (swapped acc: n = nt*16+quad*4+r, m = mt*16+ln): fx4 stores,
        // bias folded per store (loads CSE'd across mt).
        int nbase = n0 + wn * (BN / 2);
        #pragma unroll
        for (int mt = 0; mt < MT; mt++) {
            int m = m0 + wm * (BM / 2) + mt * 16 + ln;
            #pragma unroll
            for (int nt = 0; nt < NT; nt++) {
                fx4 bo4 = *(const fx4*)&bo[nbase + nt * 16 + quad * 4];
                fx4 v = acc[mt][nt] + bo4;
                *(fx4*)&Cout[(size_t)m * 1024 + nbase + nt * 16 + quad * 4] = v;
            }
        }
    }
}

// ---------------- flash attention: 2x2 wave split (q x key), fused epilogue ----------------
// v6 (verified round 11, 51.6 µs): V-fragment prefetch — all 8 LDS reads
// issued up front so PV's V-read latency overlaps QK MFMA + softmax.
__global__ __launch_bounds__(256, 4) void flash_attn(
        const short* __restrict__ Q, const short* __restrict__ Kg,
        const short* __restrict__ Vt, short* __restrict__ Ctx) {
    // 32 KB: [K buf0 | K buf1 | V buf0 | V buf1], 4096 shorts each.
    // Epilogue reuse: floats [0,2176) per-wq transpose scratch,
    // [2176,6272) o-reduce (2 x 2048), [6272,6336) l-reduce.
    __shared__ __align__(16) short SH[16384];

    int tid = threadIdx.x;
    int w = tid >> 6, l = tid & 63, quad = l >> 4, ln = l & 15;
    int wq = w & 1, wk = w >> 1;
    // XCD-aware decode: 4 bh per XCD, 32 q-blocks per bh
    int id = blockIdx.x;
    int xcd = id & 7, local = id >> 3;           // local 0..127
    int bh = xcd * 4 + (local & 3);
    int qx = local >> 2;                         // 0..31
    int qblk = qx * 64 + wq * 32;                // this wave's 32 q-rows
    int b = bh >> 4, h = bh & 15;
    const short* Qb = Q  + (size_t)bh * 2048 * 64;
    const short* Kb = Kg + (size_t)bh * 2048 * 64;
    const short* Vb = Vt + (size_t)bh * 64 * 2048;
    int swz = ln & 7;

    // Q fragments (B-operand), 32 rows
    bh8 qf[2][2];
    #pragma unroll
    for (int qt = 0; qt < 2; qt++)
        #pragma unroll
        for (int c = 0; c < 2; c++)
            qf[qt][c] = *(const bh8*)&Qb[(size_t)(qblk + qt * 16 + ln) * 64 + c * 32 + quad * 8];

    // all-ones bf16 A-fragment for the l row-sum MFMA
    union { short s[8]; bh8 v; } one_;
    #pragma unroll
    for (int j = 0; j < 8; j++) one_.s[j] = 0x3F80;
    bh8 onesv = one_.v;

    // DMA staging map (block-cooperative, by raw wave id w): chunk c = w*2+j
    // covers tile rows [c*8, c*8+8). Linear LDS dest: lane l -> c*512 + l*8.
    // Global source pre-swizzled so LDS[row][p] holds col-group p^(row&7).
    const short* srcK[2]; const short* srcV[2]; int dstoff[2];
    #pragma unroll
    for (int j = 0; j < 2; j++) {
        int c = w * 2 + j;
        int row = c * 8 + (l >> 3);
        int pg = (l & 7) ^ (row & 7);
        srcK[j] = Kb + row * 64 + pg * 8;
        srcV[j] = Vb + (size_t)row * 2048 + pg * 8;
        dstoff[j] = c * 512;
    }

    // prologue: stage tile 0 into buf 0
    #pragma unroll
    for (int j = 0; j < 2; j++) {
        gload_lds16(srcK[j], SH + dstoff[j]);
        gload_lds16(srcV[j], SH + 8192 + dstoff[j]);
    }

    fx4 o[2][4] = {};
    fx4 lacc[2] = {};

    for (int it = 0; it < 32; ++it) {
        int koff = (it & 1) ? 4096 : 0;
        // tile `it` DMA complete + all waves done reading buf it^1.
        asm volatile("s_waitcnt vmcnt(0) lgkmcnt(0)\n\ts_barrier" ::: "memory");
        if (it < 31) {   // issue next-tile DMA into the other buffer; waited next iter
            int noff = koff ^ 4096;
            int kg = (it + 1) * 4096, vg = (it + 1) * 64;
            #pragma unroll
            for (int j = 0; j < 2; j++) {
                gload_lds16(srcK[j] + kg, SH + noff + dstoff[j]);
                gload_lds16(srcV[j] + vg, SH + 8192 + noff + dstoff[j]);
            }
        }
        const short* ksb = SH + koff;
        const short* vsb = SH + 8192 + koff;

        // Issue ALL LDS reads up front: kf for QK^T, then vf for PV (vf is
        // independent of QK results — explicit ILP so PV's V-read latency
        // overlaps the QK MFMA + softmax phases).
        bh8 kf[2][2];
        #pragma unroll
        for (int mt = 0; mt < 2; mt++) {
            int krow = (wk * 32 + mt * 16 + ln) * 64;
            kf[mt][0] = *(const bh8*)&ksb[krow + ((quad ^ swz) * 8)];
            kf[mt][1] = *(const bh8*)&ksb[krow + (((quad + 4) ^ swz) * 8)];
        }
        bh8 vf[4];
        #pragma unroll
        for (int dt = 0; dt < 4; dt++)
            vf[dt] = *(const bh8*)&vsb[(dt * 16 + ln) * 64 + (((wk * 4 + quad) ^ swz) * 8)];

        // S^T[key][q] = K * Q^T  (this wave: keys wk*32.., 32 q-cols)
        fx4 s[2][2] = {};
        __builtin_amdgcn_s_setprio(1);
        #pragma unroll
        for (int mt = 0; mt < 2; mt++)
            #pragma unroll
            for (int qt = 0; qt < 2; qt++) {
                s[qt][mt] = __builtin_amdgcn_mfma_f32_16x16x32_bf16(kf[mt][0], qf[qt][0], s[qt][mt], 0, 0, 0);
                s[qt][mt] = __builtin_amdgcn_mfma_f32_16x16x32_bf16(kf[mt][1], qf[qt][1], s[qt][mt], 0, 0, 0);
            }
        __builtin_amdgcn_s_setprio(0);

        // P = exp2(S), packed to PV B-fragments entirely in-register
        bh8 pf[2];
        #pragma unroll
        for (int qt = 0; qt < 2; qt++) {
            fx4 e0, e1;
            #pragma unroll
            for (int r = 0; r < 4; r++) {
                e0[r] = __builtin_amdgcn_exp2f(s[qt][0][r]);
                e1[r] = __builtin_amdgcn_exp2f(s[qt][1][r]);
            }
            uint4 pk = pack32(e0, e1);
            union { uint4 u; bh8 v; } pc;
            pc.u = pk;
            pf[qt] = pc.v;
        }

        // O^T += V^T * P^T over this wave's 32 keys; l via ones-MFMA row-sum
        __builtin_amdgcn_s_setprio(1);
        #pragma unroll
        for (int dt = 0; dt < 4; dt++) {
            o[0][dt] = __builtin_amdgcn_mfma_f32_16x16x32_bf16(vf[dt], pf[0], o[0][dt], 0, 0, 0);
            o[1][dt] = __builtin_amdgcn_mfma_f32_16x16x32_bf16(vf[dt], pf[1], o[1][dt], 0, 0, 0);
        }
        lacc[0] = __builtin_amdgcn_mfma_f32_16x16x32_bf16(onesv, pf[0], lacc[0], 0, 0, 0);
        lacc[1] = __builtin_amdgcn_mfma_f32_16x16x32_bf16(onesv, pf[1], lacc[1], 0, 0, 0);
        __builtin_amdgcn_s_setprio(0);
    }

    // all waves done reading K/V LDS before reusing it as epilogue scratch
    asm volatile("s_waitcnt vmcnt(0) lgkmcnt(0)\n\ts_barrier" ::: "memory");

    float* R  = (float*)SH + 2176;            // o-reduce: 2 regions x 2048 floats
    float* R2 = (float*)SH + 2176 + 4096;     // l-reduce: 2 x 32 floats

    // wk=1 waves publish their key-partial O and l
    if (wk == 1) {
        float* Rw = R + wq * 2048;
        #pragma unroll
        for (int qt = 0; qt < 2; qt++)
            #pragma unroll
            for (int dt = 0; dt < 4; dt++)
                *(fx4*)&Rw[(((qt * 4 + dt) * 4 + quad) * 16 + ln) * 4] = o[qt][dt];
        if (quad == 0) {
            R2[wq * 32 + 0 * 16 + ln] = lacc[0][0];
            R2[wq * 32 + 1 * 16 + ln] = lacc[1][0];
        }
    }
    asm volatile("s_waitcnt lgkmcnt(0)\n\ts_barrier" ::: "memory");

    if (wk == 0) {
        // reduce across the wk pair
        float* Rw = R + wq * 2048;
        float linv[2];
        #pragma unroll
        for (int qt = 0; qt < 2; qt++) {
            #pragma unroll
            for (int dt = 0; dt < 4; dt++)
                o[qt][dt] += *(const fx4*)&Rw[(((qt * 4 + dt) * 4 + quad) * 16 + ln) * 4];
            float lf = lacc[qt][0] + R2[wq * 32 + qt * 16 + ln];
            linv[qt] = 1.0f / lf;
        }
        // O^T -> rows via per-wave LDS transpose, scale by 1/l, bf16 out.
        float* PsF = (float*)SH + wq * 1088;   // 16 rows x 68-float stride
        int row = l >> 2, seg = l & 3;
        #pragma unroll
        for (int qt = 0; qt < 2; qt++) {
            #pragma unroll
            for (int dt = 0; dt < 4; dt++)
                *(fx4*)&PsF[ln * 68 + dt * 16 + quad * 4] = o[qt][dt];
            asm volatile("s_waitcnt lgkmcnt(0)" ::: "memory");
            float invr = __shfl(linv[qt], row);    // lane `row` holds l for q-row `row`
            int q = qblk + qt * 16 + row;
            short* crow = Ctx + ((size_t)(b * 2048 + q)) * 1024 + h * 64 + seg * 16;
            union { short s[8]; uint4 u; } o0, o1;
            #pragma unroll
            for (int j = 0; j < 2; j++) {
                fx4 v = *(const fx4*)&PsF[row * 68 + seg * 16 + j * 4];
                o0.s[j * 4 + 0] = f2bs(v[0] * invr);
                o0.s[j * 4 + 1] = f2bs(v[1] * invr);
                o0.s[j * 4 + 2] = f2bs(v[2] * invr);
                o0.s[j * 4 + 3] = f2bs(v[3] * invr);
            }
            #pragma unroll
            for (int j = 2; j < 4; j++) {
                fx4 v = *(const fx4*)&PsF[row * 68 + seg * 16 + j * 4];
                o1.s[(j - 2) * 4 + 0] = f2bs(v[0] * invr);
                o1.s[(j - 2) * 4 + 1] = f2bs(v[1] * invr);
                o1.s[(j - 2) * 4 + 2] = f2bs(v[2] * invr);
                o1.s[(j - 2) * 4 + 3] = f2bs(v[3] * invr);
            }
            *(uint4*)&crow[0] = o0.u;
            *(uint4*)&crow[8] = o1.u;
            asm volatile("s_waitcnt lgkmcnt(0)" ::: "memory");  // reads done before next qt overwrites
        }
    }
}

extern "C" void kernel_launch(void* const* d_in, const int* in_sizes, int n_in,
                              void* d_out, int out_size, void* d_ws, size_t ws_size,
                              hipStream_t stream) {
    const float* emb = (const float*)d_in[0];
    const float* Wq  = (const float*)d_in[1];
    const float* bq  = (const float*)d_in[2];
    const float* Wk  = (const float*)d_in[3];
    const float* bk  = (const float*)d_in[4];
    const float* Wv  = (const float*)d_in[5];
    const float* bv  = (const float*)d_in[6];
    const float* Wo  = (const float*)d_in[7];
    const float* bo  = (const float*)d_in[8];

    char* ws = (char*)d_ws;
    const size_t MB = 1024 * 1024;
    short* Xbf  = (short*)(ws + 0);          // A panel for QKV gemm
    short* Ctx  = (short*)(ws + 0);          // flash bf16 output (overlays Xbf,
                                             // which is dead after the QKV gemm)
    short* Wt   = (short*)(ws + 8 * MB);
    short* Wot  = (short*)(ws + 17 * MB);
    short* Qb   = (short*)(ws + 19 * MB);    // pre-scaled by QSCALE
    short* Kb   = (short*)(ws + 27 * MB);
    short* Vtb  = (short*)(ws + 35 * MB);    // [B,H,Dh,S]

    // fused prep: emb->bf16 (4096 blocks) + 4x weight transpose (1024 blocks)
    prep<<<5120, 256, 0, stream>>>(emb, Xbf, Wq, Wk, Wv, Wo, Wt, Wot);
    // QKV projection: 128x128 tiles, 32x24 = 768 blocks, XCD-swizzled
    gemm_bt_t<128, 128, NQKV, 0><<<768, 256, 0, stream>>>(
        Xbf, Wt, bq, bk, bv, nullptr, Qb, Kb, Vtb, nullptr);
    // attention: 1024 blocks = 4/CU, 64 q-rows each, 2x2 wave split, fused bf16 out
    flash_attn<<<1024, 256, 0, stream>>>(Qb, Kb, Vtb, Ctx);
    // output projection: 64x64 tiles, 64x16 = 1024 blocks = 4/CU (was 64x128,
    // 512 blocks = 2/CU grid-starved), XCD-swizzled
    gemm_bt_t<64, 64, DMODEL, 1><<<1024, 256, 0, stream>>>(
        Ctx, Wot, nullptr, nullptr, nullptr, bo, nullptr, nullptr, nullptr, (float*)d_out);
}